// Round 1
// baseline (406.694 us; speedup 1.0000x reference)
//
#include <hip/hip_runtime.h>
#include <hip/hip_bf16.h>

typedef __attribute__((ext_vector_type(4))) float f32x4;
typedef __attribute__((ext_vector_type(8))) short s16x8;
typedef __attribute__((ext_vector_type(4))) short s16x4;

#define DM 1024
#define NH 16
#define NB 2
#define NS 2048
#define NTOK (NB*NS)

__device__ __forceinline__ float b2f(short u){
  union { unsigned int i; float f; } c; c.i = ((unsigned int)(unsigned short)u) << 16; return c.f;
}
__device__ __forceinline__ short f2b(float f){
  __hip_bfloat16 h = __float2bfloat16(f);
  return __builtin_bit_cast(short, h);
}
__device__ __forceinline__ void gload16(const void* g, void* l){
  __builtin_amdgcn_global_load_lds((const __attribute__((address_space(1))) void*)g,
                                   (__attribute__((address_space(3))) void*)l, 16, 0, 0);
}

// ---------------- GEMM: C[M,N] = A[M,K](bf16) * Bt[N,K](bf16)^T + bias ----------------
template<int GELU, int OUTBF16>
__global__ __launch_bounds__(256,2) void gemm_bt(
    const short* __restrict__ A, const short* __restrict__ Bt,
    const float* __restrict__ bias, void* __restrict__ Cv,
    int M, int N, int K)
{
  __shared__ short Al[128*64];
  __shared__ short Bl[128*64];
  int tid = threadIdx.x, wid = tid>>6, lane = tid&63;
  int la = lane&15, lb = lane>>4;
  int nbn = N>>7;
  int bm = (int)blockIdx.x / nbn, bn = (int)blockIdx.x % nbn;
  int wm = (wid>>1)<<6, wn = (wid&1)<<6;
  f32x4 acc[4][4] = {};
  for (int kt=0; kt<K; kt+=64){
    #pragma unroll
    for (int i=0;i<4;i++){
      int c = i*256+tid; int r=c>>3, col=(c&7)<<3;
      gload16(A + (size_t)(bm*128+r)*K + kt + col, &Al[(i*256+wid*64)*8]);
    }
    #pragma unroll
    for (int i=0;i<4;i++){
      int c = i*256+tid; int r=c>>3, col=(c&7)<<3;
      gload16(Bt + (size_t)(bn*128+r)*K + kt + col, &Bl[(i*256+wid*64)*8]);
    }
    __syncthreads();
    #pragma unroll
    for (int ks=0;ks<64;ks+=32){
      s16x8 af[4], bfr[4];
      #pragma unroll
      for (int mi=0;mi<4;mi++) af[mi]  = *(const s16x8*)&Al[(wm+mi*16+la)*64 + ks + lb*8];
      #pragma unroll
      for (int ni=0;ni<4;ni++) bfr[ni] = *(const s16x8*)&Bl[(wn+ni*16+la)*64 + ks + lb*8];
      #pragma unroll
      for (int mi=0;mi<4;mi++)
        #pragma unroll
        for (int ni=0;ni<4;ni++)
          acc[mi][ni] = __builtin_amdgcn_mfma_f32_16x16x32_bf16(af[mi], bfr[ni], acc[mi][ni], 0,0,0);
    }
    __syncthreads();
  }
  #pragma unroll
  for (int ni=0;ni<4;ni++){
    int col = bn*128 + wn + ni*16 + la;
    float bv = bias[col];
    #pragma unroll
    for (int mi=0;mi<4;mi++){
      int row0 = bm*128 + wm + mi*16 + lb*4;
      #pragma unroll
      for (int j=0;j<4;j++){
        float v = acc[mi][ni][j] + bv;
        if (GELU) v = 0.5f*v*(1.0f + erff(v*0.70710678118f));
        if (OUTBF16) ((short*)Cv)[(size_t)(row0+j)*N + col] = f2b(v);
        else ((float*)Cv)[(size_t)(row0+j)*N + col] = v;
      }
    }
  }
}

// ---------------- Flash attention: qkv bf16 [NTOK,3*DM] -> ctx bf16 [NTOK,DM] ----------------
__global__ __launch_bounds__(256,2) void attn_fwd(const short* __restrict__ qkv, short* __restrict__ ctx)
{
  __shared__ short Kl[64*64];
  __shared__ short Vt[64*66];      // Vt[d][kv], stride 66 pad
  __shared__ short Pl[4*16*72];    // per-wave P tile, stride 72 (16B-aligned rows)
  int tid=threadIdx.x, wid=tid>>6, lane=tid&63;
  int la = lane&15, lb = lane>>4;
  int qt = blockIdx.x, bh = blockIdx.y;
  int b = bh>>4, h = bh&15;
  int q0 = qt*64 + wid*16;
  const size_t qrow = (size_t)(b*NS + q0 + la)*3072 + h*64 + lb*8;
  s16x8 qf0 = *(const s16x8*)(qkv + qrow);
  s16x8 qf1 = *(const s16x8*)(qkv + qrow + 32);
  #pragma unroll
  for (int i=0;i<8;i++){ qf0[i] = f2b(b2f(qf0[i])*0.125f); qf1[i] = f2b(b2f(qf1[i])*0.125f); }
  f32x4 cacc[4] = {};
  float mrow[4] = {-1e30f,-1e30f,-1e30f,-1e30f};
  float lrow[4] = {0.f,0.f,0.f,0.f};
  for (int t=0; t<NS/64; t++){
    #pragma unroll
    for (int i=0;i<2;i++){
      int c = i*256+tid; int r=c>>3, col=(c&7)<<3;
      size_t base = (size_t)(b*NS + t*64 + r)*3072 + h*64 + col;
      *(s16x8*)&Kl[r*64+col] = *(const s16x8*)(qkv + base + 1024);
      s16x8 vv = *(const s16x8*)(qkv + base + 2048);
      #pragma unroll
      for (int j=0;j<8;j++) Vt[(col+j)*66 + r] = vv[j];
    }
    __syncthreads();
    f32x4 sacc[4] = {};
    #pragma unroll
    for (int nk=0;nk<4;nk++){
      s16x8 kf0 = *(const s16x8*)&Kl[(nk*16+la)*64 + lb*8];
      s16x8 kf1 = *(const s16x8*)&Kl[(nk*16+la)*64 + 32 + lb*8];
      sacc[nk] = __builtin_amdgcn_mfma_f32_16x16x32_bf16(qf0, kf0, sacc[nk], 0,0,0);
      sacc[nk] = __builtin_amdgcn_mfma_f32_16x16x32_bf16(qf1, kf1, sacc[nk], 0,0,0);
    }
    float corr[4];
    #pragma unroll
    for (int j=0;j<4;j++){
      float tm = fmaxf(fmaxf(sacc[0][j],sacc[1][j]),fmaxf(sacc[2][j],sacc[3][j]));
      tm = fmaxf(tm, __shfl_xor(tm,1,64));
      tm = fmaxf(tm, __shfl_xor(tm,2,64));
      tm = fmaxf(tm, __shfl_xor(tm,4,64));
      tm = fmaxf(tm, __shfl_xor(tm,8,64));
      float mn = fmaxf(mrow[j], tm);
      corr[j] = __expf(mrow[j]-mn);
      mrow[j]=mn;
      float rs = 0.f;
      #pragma unroll
      for (int nk=0;nk<4;nk++){ float p = __expf(sacc[nk][j]-mn); sacc[nk][j]=p; rs += p; }
      rs += __shfl_xor(rs,1,64); rs += __shfl_xor(rs,2,64);
      rs += __shfl_xor(rs,4,64); rs += __shfl_xor(rs,8,64);
      lrow[j] = lrow[j]*corr[j] + rs;
    }
    #pragma unroll
    for (int nd=0;nd<4;nd++)
      #pragma unroll
      for (int j=0;j<4;j++) cacc[nd][j] *= corr[j];
    // P -> LDS (per-wave), then read back as MFMA A-fragments
    #pragma unroll
    for (int nk=0;nk<4;nk++)
      #pragma unroll
      for (int j=0;j<4;j++)
        Pl[wid*16*72 + (lb*4+j)*72 + la + 16*nk] = f2b(sacc[nk][j]);
    s16x8 pf0 = *(const s16x8*)&Pl[wid*16*72 + la*72 + lb*8];
    s16x8 pf1 = *(const s16x8*)&Pl[wid*16*72 + la*72 + 32 + lb*8];
    #pragma unroll
    for (int nd=0;nd<4;nd++){
      int d = la + 16*nd;
      const int* vp  = (const int*)&Vt[d*66 + lb*8];
      const int* vp2 = (const int*)&Vt[d*66 + 32 + lb*8];
      union { int i[4]; s16x8 v; } u0, u1;
      u0.i[0]=vp[0];  u0.i[1]=vp[1];  u0.i[2]=vp[2];  u0.i[3]=vp[3];
      u1.i[0]=vp2[0]; u1.i[1]=vp2[1]; u1.i[2]=vp2[2]; u1.i[3]=vp2[3];
      cacc[nd] = __builtin_amdgcn_mfma_f32_16x16x32_bf16(pf0, u0.v, cacc[nd], 0,0,0);
      cacc[nd] = __builtin_amdgcn_mfma_f32_16x16x32_bf16(pf1, u1.v, cacc[nd], 0,0,0);
    }
    __syncthreads();
  }
  #pragma unroll
  for (int nd=0;nd<4;nd++){
    int dcol = h*64 + nd*16 + la;
    #pragma unroll
    for (int j=0;j<4;j++){
      int row = b*NS + q0 + lb*4 + j;
      ctx[(size_t)row*DM + dcol] = f2b(cacc[nd][j] / lrow[j]);
    }
  }
}

// ---------------- LayerNorm kernels ----------------
__device__ __forceinline__ void wred2(float& s, float& ss){
  #pragma unroll
  for (int m=1;m<64;m<<=1){ s += __shfl_xor(s,m,64); ss += __shfl_xor(ss,m,64); }
}

__global__ __launch_bounds__(256) void ln_in(const float* __restrict__ x,
    const float* __restrict__ g, const float* __restrict__ be, short* __restrict__ out)
{
  int row=blockIdx.x, tid=threadIdx.x;
  __shared__ float r1[4], r2[4];
  float4 v = ((const float4*)(x + (size_t)row*DM))[tid];
  float s=v.x+v.y+v.z+v.w, ss=v.x*v.x+v.y*v.y+v.z*v.z+v.w*v.w;
  wred2(s,ss);
  if ((tid&63)==0){ r1[tid>>6]=s; r2[tid>>6]=ss; }
  __syncthreads();
  s=r1[0]+r1[1]+r1[2]+r1[3]; ss=r2[0]+r2[1]+r2[2]+r2[3];
  float mu=s*(1.f/DM);
  float rstd=rsqrtf(ss*(1.f/DM)-mu*mu+1e-5f);
  float4 gv=((const float4*)g)[tid], bv=((const float4*)be)[tid];
  s16x4 o;
  o[0]=f2b((v.x-mu)*rstd*gv.x+bv.x);
  o[1]=f2b((v.y-mu)*rstd*gv.y+bv.y);
  o[2]=f2b((v.z-mu)*rstd*gv.z+bv.z);
  o[3]=f2b((v.w-mu)*rstd*gv.w+bv.w);
  *(s16x4*)(out + (size_t)row*DM + tid*4) = o;
}

// x1 = LN(x+ao, g1,b1) [f32]; h2 = bf16(LN(x1, g2,b2))
__global__ __launch_bounds__(256) void ln_chain(const float* __restrict__ x, const float* __restrict__ ao,
    const float* __restrict__ g1, const float* __restrict__ be1,
    const float* __restrict__ g2, const float* __restrict__ be2,
    float* __restrict__ x1, short* __restrict__ h2)
{
  int row=blockIdx.x, tid=threadIdx.x;
  __shared__ float r1[4], r2[4], r3[4], r4[4];
  float4 xv = ((const float4*)(x + (size_t)row*DM))[tid];
  float4 av = ((const float4*)(ao + (size_t)row*DM))[tid];
  float4 y; y.x=xv.x+av.x; y.y=xv.y+av.y; y.z=xv.z+av.z; y.w=xv.w+av.w;
  float s=y.x+y.y+y.z+y.w, ss=y.x*y.x+y.y*y.y+y.z*y.z+y.w*y.w;
  wred2(s,ss);
  if ((tid&63)==0){ r1[tid>>6]=s; r2[tid>>6]=ss; }
  __syncthreads();
  s=r1[0]+r1[1]+r1[2]+r1[3]; ss=r2[0]+r2[1]+r2[2]+r2[3];
  float mu=s*(1.f/DM);
  float rstd=rsqrtf(ss*(1.f/DM)-mu*mu+1e-5f);
  float4 g1v=((const float4*)g1)[tid], b1v=((const float4*)be1)[tid];
  float4 xo;
  xo.x=(y.x-mu)*rstd*g1v.x+b1v.x;
  xo.y=(y.y-mu)*rstd*g1v.y+b1v.y;
  xo.z=(y.z-mu)*rstd*g1v.z+b1v.z;
  xo.w=(y.w-mu)*rstd*g1v.w+b1v.w;
  ((float4*)(x1 + (size_t)row*DM))[tid] = xo;
  float s2=xo.x+xo.y+xo.z+xo.w, ss2=xo.x*xo.x+xo.y*xo.y+xo.z*xo.z+xo.w*xo.w;
  wred2(s2,ss2);
  if ((tid&63)==0){ r3[tid>>6]=s2; r4[tid>>6]=ss2; }
  __syncthreads();
  s2=r3[0]+r3[1]+r3[2]+r3[3]; ss2=r4[0]+r4[1]+r4[2]+r4[3];
  float mu2=s2*(1.f/DM);
  float rstd2=rsqrtf(ss2*(1.f/DM)-mu2*mu2+1e-5f);
  float4 g2v=((const float4*)g2)[tid], b2v=((const float4*)be2)[tid];
  s16x4 o;
  o[0]=f2b((xo.x-mu2)*rstd2*g2v.x+b2v.x);
  o[1]=f2b((xo.y-mu2)*rstd2*g2v.y+b2v.y);
  o[2]=f2b((xo.z-mu2)*rstd2*g2v.z+b2v.z);
  o[3]=f2b((xo.w-mu2)*rstd2*g2v.w+b2v.w);
  *(s16x4*)(h2 + (size_t)row*DM + tid*4) = o;
}

// out = LN(a+bsrc, g, be) [f32]
__global__ __launch_bounds__(256) void ln_out_k(const float* __restrict__ a, const float* __restrict__ bsrc,
    const float* __restrict__ g, const float* __restrict__ be, float* __restrict__ out)
{
  int row=blockIdx.x, tid=threadIdx.x;
  __shared__ float r1[4], r2[4];
  float4 xv = ((const float4*)(a + (size_t)row*DM))[tid];
  float4 av = ((const float4*)(bsrc + (size_t)row*DM))[tid];
  float4 y; y.x=xv.x+av.x; y.y=xv.y+av.y; y.z=xv.z+av.z; y.w=xv.w+av.w;
  float s=y.x+y.y+y.z+y.w, ss=y.x*y.x+y.y*y.y+y.z*y.z+y.w*y.w;
  wred2(s,ss);
  if ((tid&63)==0){ r1[tid>>6]=s; r2[tid>>6]=ss; }
  __syncthreads();
  s=r1[0]+r1[1]+r1[2]+r1[3]; ss=r2[0]+r2[1]+r2[2]+r2[3];
  float mu=s*(1.f/DM);
  float rstd=rsqrtf(ss*(1.f/DM)-mu*mu+1e-5f);
  float4 gv=((const float4*)g)[tid], bv=((const float4*)be)[tid];
  float4 o;
  o.x=(y.x-mu)*rstd*gv.x+bv.x;
  o.y=(y.y-mu)*rstd*gv.y+bv.y;
  o.z=(y.z-mu)*rstd*gv.z+bv.z;
  o.w=(y.w-mu)*rstd*gv.w+bv.w;
  ((float4*)(out + (size_t)row*DM))[tid] = o;
}

// ---------------- cast + transpose: w[R][C] f32 -> wt[C][R] bf16 ----------------
__global__ __launch_bounds__(256) void cast_t(const float* __restrict__ w, short* __restrict__ wt, int R, int C)
{
  __shared__ short t[64][65];
  int nbr = R>>6;
  int br = (int)blockIdx.x % nbr, bc = (int)blockIdx.x / nbr;
  int tid = threadIdx.x;
  #pragma unroll
  for (int i=0;i<4;i++){
    int c = i*256 + tid;
    int r = c>>4, c4 = (c&15)*4;
    float4 v = *(const float4*)(w + (size_t)(br*64 + r)*C + bc*64 + c4);
    t[r][c4+0]=f2b(v.x); t[r][c4+1]=f2b(v.y); t[r][c4+2]=f2b(v.z); t[r][c4+3]=f2b(v.w);
  }
  __syncthreads();
  #pragma unroll
  for (int i=0;i<4;i++){
    int c = i*256 + tid;
    int oc = c>>4, c4 = (c&15)*4;
    s16x4 p;
    p[0]=t[c4+0][oc]; p[1]=t[c4+1][oc]; p[2]=t[c4+2][oc]; p[3]=t[c4+3][oc];
    *(s16x4*)&wt[(size_t)(bc*64 + oc)*R + br*64 + c4] = p;
  }
}

// ---------------- launcher ----------------
extern "C" void kernel_launch(void* const* d_in, const int* in_sizes, int n_in,
                              void* d_out, int out_size, void* d_ws, size_t ws_size,
                              hipStream_t stream)
{
  const float* x      = (const float*)d_in[0];
  const float* qkv_w  = (const float*)d_in[1];
  const float* qkv_b  = (const float*)d_in[2];
  const float* out_w  = (const float*)d_in[3];
  const float* out_b  = (const float*)d_in[4];
  const float* aln_g  = (const float*)d_in[5];
  const float* aln_b  = (const float*)d_in[6];
  const float* n1_g   = (const float*)d_in[7];
  const float* n1_b   = (const float*)d_in[8];
  const float* fln_g  = (const float*)d_in[9];
  const float* fln_b  = (const float*)d_in[10];
  const float* w1     = (const float*)d_in[11];
  const float* b1     = (const float*)d_in[12];
  const float* w2     = (const float*)d_in[13];
  const float* b2     = (const float*)d_in[14];
  const float* n2_g   = (const float*)d_in[15];
  const float* n2_b   = (const float*)d_in[16];

  char* ws = (char*)d_ws;
  short* wqkvT = (short*)(ws + 0);          // [3072][1024] bf16
  short* woutT = (short*)(ws + 6291456);    // [1024][1024]
  short* w1T   = (short*)(ws + 8388608);    // [4096][1024]
  short* w2T   = (short*)(ws + 16777216);   // [1024][4096]
  short* h1    = (short*)(ws + 25165824);   // [4096][1024] bf16 (reused as h2)
  short* qkv   = (short*)(ws + 33554432);   // [4096][3072] bf16
  float* attn_out = (float*)(ws + 33554432);// aliases qkv (dead by then)
  short* ff1   = (short*)(ws + 33554432);   // [4096][4096] bf16, aliases qkv+ctx
  short* ctx   = (short*)(ws + 58720256);   // [4096][1024] bf16
  float* x1    = (float*)(ws + 67108864);   // [4096][1024] f32
  float* ff2   = (float*)(ws + 83886080);   // [4096][1024] f32
  float* outp  = (float*)d_out;

  cast_t<<<dim3(16*48),256,0,stream>>>(qkv_w, wqkvT, 1024, 3072);
  cast_t<<<dim3(16*16),256,0,stream>>>(out_w, woutT, 1024, 1024);
  cast_t<<<dim3(16*64),256,0,stream>>>(w1,    w1T,   1024, 4096);
  cast_t<<<dim3(64*16),256,0,stream>>>(w2,    w2T,   4096, 1024);

  ln_in<<<NTOK,256,0,stream>>>(x, aln_g, aln_b, h1);
  gemm_bt<0,1><<<dim3(32*24),256,0,stream>>>(h1, wqkvT, qkv_b, qkv, 4096,3072,1024);
  attn_fwd<<<dim3(32,32),256,0,stream>>>(qkv, ctx);
  gemm_bt<0,0><<<dim3(32*8),256,0,stream>>>(ctx, woutT, out_b, attn_out, 4096,1024,1024);
  ln_chain<<<NTOK,256,0,stream>>>(x, attn_out, n1_g, n1_b, fln_g, fln_b, x1, h1);
  gemm_bt<1,1><<<dim3(32*32),256,0,stream>>>(h1, w1T, b1, ff1, 4096,4096,1024);
  gemm_bt<0,0><<<dim3(32*8),256,0,stream>>>(ff1, w2T, b2, ff2, 4096,1024,4096);
  ln_out_k<<<NTOK,256,0,stream>>>(x1, ff2, n2_g, n2_b, outp);
}

// Round 2
// 357.506 us; speedup vs baseline: 1.1376x; 1.1376x over previous
//
#include <hip/hip_runtime.h>
#include <hip/hip_bf16.h>

typedef __attribute__((ext_vector_type(4))) float f32x4;
typedef __attribute__((ext_vector_type(8))) short s16x8;
typedef __attribute__((ext_vector_type(4))) short s16x4;

#define DM 1024
#define NH 16
#define NB 2
#define NS 2048
#define NTOK (NB*NS)

__device__ __forceinline__ float b2f(short u){
  union { unsigned int i; float f; } c; c.i = ((unsigned int)(unsigned short)u) << 16; return c.f;
}
__device__ __forceinline__ short f2b(float f){
  __hip_bfloat16 h = __float2bfloat16(f);
  return __builtin_bit_cast(short, h);
}
__device__ __forceinline__ void gload16(const void* g, void* l){
  __builtin_amdgcn_global_load_lds((const __attribute__((address_space(1))) void*)g,
                                   (__attribute__((address_space(3))) void*)l, 16, 0, 0);
}
// hardware transpose read: lane l gets elems base_e + (l&15) + j*16 + (l>>4)*64
__device__ __forceinline__ s16x4 tr16(const void* p){
  s16x4 r;
  asm volatile("ds_read_b64_tr_b16 %0, %1"
               : "=v"(r)
               : "v"((const __attribute__((address_space(3))) short*)p)
               : "memory");
  return r;
}

// ---------------- GEMM: C[M,N] = A[M,K](bf16) * Bt[N,K](bf16)^T + bias ----------------
template<int GELU, int OUTBF16>
__global__ __launch_bounds__(256,2) void gemm_bt(
    const short* __restrict__ A, const short* __restrict__ Bt,
    const float* __restrict__ bias, void* __restrict__ Cv,
    int M, int N, int K)
{
  __shared__ short Al[128*64];
  __shared__ short Bl[128*64];
  int tid = threadIdx.x, wid = tid>>6, lane = tid&63;
  int la = lane&15, lb = lane>>4;
  int nbn = N>>7;
  int bm = (int)blockIdx.x / nbn, bn = (int)blockIdx.x % nbn;
  int wm = (wid>>1)<<6, wn = (wid&1)<<6;
  f32x4 acc[4][4] = {};
  for (int kt=0; kt<K; kt+=64){
    #pragma unroll
    for (int i=0;i<4;i++){
      int c = i*256+tid; int r=c>>3, col=(c&7)<<3;
      gload16(A + (size_t)(bm*128+r)*K + kt + col, &Al[(i*256+wid*64)*8]);
    }
    #pragma unroll
    for (int i=0;i<4;i++){
      int c = i*256+tid; int r=c>>3, col=(c&7)<<3;
      gload16(Bt + (size_t)(bn*128+r)*K + kt + col, &Bl[(i*256+wid*64)*8]);
    }
    __syncthreads();
    #pragma unroll
    for (int ks=0;ks<64;ks+=32){
      s16x8 af[4], bfr[4];
      #pragma unroll
      for (int mi=0;mi<4;mi++) af[mi]  = *(const s16x8*)&Al[(wm+mi*16+la)*64 + ks + lb*8];
      #pragma unroll
      for (int ni=0;ni<4;ni++) bfr[ni] = *(const s16x8*)&Bl[(wn+ni*16+la)*64 + ks + lb*8];
      #pragma unroll
      for (int mi=0;mi<4;mi++)
        #pragma unroll
        for (int ni=0;ni<4;ni++)
          acc[mi][ni] = __builtin_amdgcn_mfma_f32_16x16x32_bf16(af[mi], bfr[ni], acc[mi][ni], 0,0,0);
    }
    __syncthreads();
  }
  #pragma unroll
  for (int ni=0;ni<4;ni++){
    int col = bn*128 + wn + ni*16 + la;
    float bv = bias[col];
    #pragma unroll
    for (int mi=0;mi<4;mi++){
      int row0 = bm*128 + wm + mi*16 + lb*4;
      #pragma unroll
      for (int j=0;j<4;j++){
        float v = acc[mi][ni][j] + bv;
        if (GELU) v = 0.5f*v*(1.0f + erff(v*0.70710678118f));
        if (OUTBF16) ((short*)Cv)[(size_t)(row0+j)*N + col] = f2b(v);
        else ((float*)Cv)[(size_t)(row0+j)*N + col] = v;
      }
    }
  }
}

// ---------------- Flash attention: qkv bf16 [NTOK,3*DM] -> ctx bf16 [NTOK,DM] ----------------
// K tile: [64][64] bf16, XOR-swizzled (byte ^= (row&7)<<4) via pre-swizzled global src.
// V tile: tr-subtiled layout f(k,d) = (d>>4)*1024 + ((k>>2)&1)*512 + (k>>3)*64 + (k&3)*16 + (d&15)
//         so ds_read_b64_tr_b16 at byte base (nd*2048 + jh*1024 + ks*512) + lane*8 yields
//         elems V[ks*32 + lb*8 + jh*4 + j][nd*16 + la]  (lb=lane>>4, la=lane&15, j=0..3).
__global__ __launch_bounds__(256,3) void attn_fwd(const short* __restrict__ qkv, short* __restrict__ ctx)
{
  __shared__ short Kl[2][4096];
  __shared__ short Vl[2][4096];
  __shared__ short Pl[4608];          // 4 waves x [16][72]
  int tid=threadIdx.x, wid=tid>>6, lane=tid&63;
  int la = lane&15, lb = lane>>4;
  int qt = blockIdx.x, bh = blockIdx.y;
  int b = bh>>4, h = bh&15;
  int q0 = qt*64 + wid*16;

  const size_t qrow = (size_t)(b*NS + q0 + la)*3072 + h*64 + lb*8;
  s16x8 qf0 = *(const s16x8*)(qkv + qrow);
  s16x8 qf1 = *(const s16x8*)(qkv + qrow + 32);
  #pragma unroll
  for (int i=0;i<8;i++){ qf0[i] = f2b(b2f(qf0[i])*0.125f); qf1[i] = f2b(b2f(qf1[i])*0.125f); }

  f32x4 cacc[4] = {};
  float mrow[4] = {-1e30f,-1e30f,-1e30f,-1e30f};
  float lrow[4] = {0.f,0.f,0.f,0.f};

  // stage tile t into buffer bf
  auto stage = [&](int t, int bf){
    #pragma unroll
    for (int i=0;i<2;i++){
      int p = (i*256 + tid)*16;                    // byte slot in K tile
      int row = p>>7, inner = p&127;
      int srcb = inner ^ ((row&7)<<4);             // inverse swizzle on source
      const short* src = qkv + (size_t)(b*NS + t*64 + row)*3072 + h*64 + 1024 + (srcb>>1);
      gload16(src, (char*)&Kl[bf][0] + (i*256 + wid*64)*16);
    }
    #pragma unroll
    for (int i=0;i<2;i++){
      int e = (i*256 + tid)*8;                     // element slot in V tile
      int dd = e>>10, kh=(e>>9)&1, kb3=(e>>6)&7, kj=(e>>4)&3, dlo=e&15;
      int k = kb3*8 + kh*4 + kj, d = dd*16 + dlo;
      const short* src = qkv + (size_t)(b*NS + t*64 + k)*3072 + h*64 + 2048 + d;
      gload16(src, (char*)&Vl[bf][0] + (i*256 + wid*64)*16);
    }
  };

  stage(0, 0);
  __syncthreads();
  int cur = 0;

  for (int t=0; t<NS/64; t++){
    if (t+1 < NS/64) stage(t+1, cur^1);

    // ---- QK^T from swizzled K ----
    const char* Kb = (const char*)&Kl[cur][0];
    f32x4 sacc[4] = {};
    #pragma unroll
    for (int nk=0;nk<4;nk++){
      int r = nk*16+la;
      int sw = (r&7)<<4;
      s16x8 kf0 = *(const s16x8*)(Kb + r*128 + ((lb*16) ^ sw));
      s16x8 kf1 = *(const s16x8*)(Kb + r*128 + ((64 + lb*16) ^ sw));
      sacc[nk] = __builtin_amdgcn_mfma_f32_16x16x32_bf16(qf0, kf0, sacc[nk], 0,0,0);
      sacc[nk] = __builtin_amdgcn_mfma_f32_16x16x32_bf16(qf1, kf1, sacc[nk], 0,0,0);
    }

    // ---- online softmax with defer-max (THR=8) ----
    float tloc[4];
    #pragma unroll
    for (int j=0;j<4;j++)
      tloc[j] = fmaxf(fmaxf(sacc[0][j],sacc[1][j]),fmaxf(sacc[2][j],sacc[3][j]));
    float excess = fmaxf(fmaxf(tloc[0]-mrow[0],tloc[1]-mrow[1]),
                         fmaxf(tloc[2]-mrow[2],tloc[3]-mrow[3]));
    if (__any(excess > 8.f)){
      #pragma unroll
      for (int j=0;j<4;j++){
        float tm = tloc[j];
        tm = fmaxf(tm, __shfl_xor(tm,1,64));
        tm = fmaxf(tm, __shfl_xor(tm,2,64));
        tm = fmaxf(tm, __shfl_xor(tm,4,64));
        tm = fmaxf(tm, __shfl_xor(tm,8,64));
        float mn = fmaxf(mrow[j], tm);
        float c = __expf(mrow[j]-mn);
        mrow[j] = mn; lrow[j] *= c;
        #pragma unroll
        for (int nd=0;nd<4;nd++) cacc[nd][j] *= c;
      }
    }
    #pragma unroll
    for (int j=0;j<4;j++){
      float rs = 0.f;
      #pragma unroll
      for (int nk=0;nk<4;nk++){ float p = __expf(sacc[nk][j]-mrow[j]); sacc[nk][j]=p; rs += p; }
      rs += __shfl_xor(rs,1,64); rs += __shfl_xor(rs,2,64);
      rs += __shfl_xor(rs,4,64); rs += __shfl_xor(rs,8,64);
      lrow[j] += rs;
    }

    // ---- P -> per-wave LDS, read back as A-fragments ----
    #pragma unroll
    for (int nk=0;nk<4;nk++)
      #pragma unroll
      for (int j=0;j<4;j++)
        Pl[wid*1152 + (lb*4+j)*72 + la + 16*nk] = f2b(sacc[nk][j]);
    s16x8 pf0 = *(const s16x8*)&Pl[wid*1152 + la*72 + lb*8];
    s16x8 pf1 = *(const s16x8*)&Pl[wid*1152 + la*72 + 32 + lb*8];

    // ---- V fragments via hardware transpose read ----
    const char* Vb = (const char*)&Vl[cur][0];
    s16x4 tv[4][4];
    #pragma unroll
    for (int nd=0;nd<4;nd++)
      #pragma unroll
      for (int q=0;q<4;q++){
        int ks = q>>1, jh = q&1;
        tv[nd][q] = tr16(Vb + nd*2048 + jh*1024 + ks*512 + lane*8);
      }
    asm volatile("s_waitcnt lgkmcnt(0)" ::: "memory");
    __builtin_amdgcn_sched_barrier(0);

    #pragma unroll
    for (int nd=0;nd<4;nd++){
      union { s16x4 h[2]; s16x8 v; } u0, u1;
      u0.h[0]=tv[nd][0]; u0.h[1]=tv[nd][1];   // ks=0: jh=0 (k 0..3 of 8), jh=1 (k 4..7)
      u1.h[0]=tv[nd][2]; u1.h[1]=tv[nd][3];   // ks=1
      cacc[nd] = __builtin_amdgcn_mfma_f32_16x16x32_bf16(pf0, u0.v, cacc[nd], 0,0,0);
      cacc[nd] = __builtin_amdgcn_mfma_f32_16x16x32_bf16(pf1, u1.v, cacc[nd], 0,0,0);
    }

    __syncthreads();
    cur ^= 1;
  }

  #pragma unroll
  for (int nd=0;nd<4;nd++){
    int dcol = h*64 + nd*16 + la;
    #pragma unroll
    for (int j=0;j<4;j++){
      int row = b*NS + q0 + lb*4 + j;
      ctx[(size_t)row*DM + dcol] = f2b(cacc[nd][j] / lrow[j]);
    }
  }
}

// ---------------- LayerNorm kernels ----------------
__device__ __forceinline__ void wred2(float& s, float& ss){
  #pragma unroll
  for (int m=1;m<64;m<<=1){ s += __shfl_xor(s,m,64); ss += __shfl_xor(ss,m,64); }
}

__global__ __launch_bounds__(256) void ln_in(const float* __restrict__ x,
    const float* __restrict__ g, const float* __restrict__ be, short* __restrict__ out)
{
  int row=blockIdx.x, tid=threadIdx.x;
  __shared__ float r1[4], r2[4];
  float4 v = ((const float4*)(x + (size_t)row*DM))[tid];
  float s=v.x+v.y+v.z+v.w, ss=v.x*v.x+v.y*v.y+v.z*v.z+v.w*v.w;
  wred2(s,ss);
  if ((tid&63)==0){ r1[tid>>6]=s; r2[tid>>6]=ss; }
  __syncthreads();
  s=r1[0]+r1[1]+r1[2]+r1[3]; ss=r2[0]+r2[1]+r2[2]+r2[3];
  float mu=s*(1.f/DM);
  float rstd=rsqrtf(ss*(1.f/DM)-mu*mu+1e-5f);
  float4 gv=((const float4*)g)[tid], bv=((const float4*)be)[tid];
  s16x4 o;
  o[0]=f2b((v.x-mu)*rstd*gv.x+bv.x);
  o[1]=f2b((v.y-mu)*rstd*gv.y+bv.y);
  o[2]=f2b((v.z-mu)*rstd*gv.z+bv.z);
  o[3]=f2b((v.w-mu)*rstd*gv.w+bv.w);
  *(s16x4*)(out + (size_t)row*DM + tid*4) = o;
}

// x1 = LN(x+ao, g1,b1) [f32]; h2 = bf16(LN(x1, g2,b2))
__global__ __launch_bounds__(256) void ln_chain(const float* __restrict__ x, const float* __restrict__ ao,
    const float* __restrict__ g1, const float* __restrict__ be1,
    const float* __restrict__ g2, const float* __restrict__ be2,
    float* __restrict__ x1, short* __restrict__ h2)
{
  int row=blockIdx.x, tid=threadIdx.x;
  __shared__ float r1[4], r2[4], r3[4], r4[4];
  float4 xv = ((const float4*)(x + (size_t)row*DM))[tid];
  float4 av = ((const float4*)(ao + (size_t)row*DM))[tid];
  float4 y; y.x=xv.x+av.x; y.y=xv.y+av.y; y.z=xv.z+av.z; y.w=xv.w+av.w;
  float s=y.x+y.y+y.z+y.w, ss=y.x*y.x+y.y*y.y+y.z*y.z+y.w*y.w;
  wred2(s,ss);
  if ((tid&63)==0){ r1[tid>>6]=s; r2[tid>>6]=ss; }
  __syncthreads();
  s=r1[0]+r1[1]+r1[2]+r1[3]; ss=r2[0]+r2[1]+r2[2]+r2[3];
  float mu=s*(1.f/DM);
  float rstd=rsqrtf(ss*(1.f/DM)-mu*mu+1e-5f);
  float4 g1v=((const float4*)g1)[tid], b1v=((const float4*)be1)[tid];
  float4 xo;
  xo.x=(y.x-mu)*rstd*g1v.x+b1v.x;
  xo.y=(y.y-mu)*rstd*g1v.y+b1v.y;
  xo.z=(y.z-mu)*rstd*g1v.z+b1v.z;
  xo.w=(y.w-mu)*rstd*g1v.w+b1v.w;
  ((float4*)(x1 + (size_t)row*DM))[tid] = xo;
  float s2=xo.x+xo.y+xo.z+xo.w, ss2=xo.x*xo.x+xo.y*xo.y+xo.z*xo.z+xo.w*xo.w;
  wred2(s2,ss2);
  if ((tid&63)==0){ r3[tid>>6]=s2; r4[tid>>6]=ss2; }
  __syncthreads();
  s2=r3[0]+r3[1]+r3[2]+r3[3]; ss2=r4[0]+r4[1]+r4[2]+r4[3];
  float mu2=s2*(1.f/DM);
  float rstd2=rsqrtf(ss2*(1.f/DM)-mu2*mu2+1e-5f);
  float4 g2v=((const float4*)g2)[tid], b2v=((const float4*)be2)[tid];
  s16x4 o;
  o[0]=f2b((xo.x-mu2)*rstd2*g2v.x+b2v.x);
  o[1]=f2b((xo.y-mu2)*rstd2*g2v.y+b2v.y);
  o[2]=f2b((xo.z-mu2)*rstd2*g2v.z+b2v.z);
  o[3]=f2b((xo.w-mu2)*rstd2*g2v.w+b2v.w);
  *(s16x4*)(h2 + (size_t)row*DM + tid*4) = o;
}

// out = LN(a+bsrc, g, be) [f32]
__global__ __launch_bounds__(256) void ln_out_k(const float* __restrict__ a, const float* __restrict__ bsrc,
    const float* __restrict__ g, const float* __restrict__ be, float* __restrict__ out)
{
  int row=blockIdx.x, tid=threadIdx.x;
  __shared__ float r1[4], r2[4];
  float4 xv = ((const float4*)(a + (size_t)row*DM))[tid];
  float4 av = ((const float4*)(bsrc + (size_t)row*DM))[tid];
  float4 y; y.x=xv.x+av.x; y.y=xv.y+av.y; y.z=xv.z+av.z; y.w=xv.w+av.w;
  float s=y.x+y.y+y.z+y.w, ss=y.x*y.x+y.y*y.y+y.z*y.z+y.w*y.w;
  wred2(s,ss);
  if ((tid&63)==0){ r1[tid>>6]=s; r2[tid>>6]=ss; }
  __syncthreads();
  s=r1[0]+r1[1]+r1[2]+r1[3]; ss=r2[0]+r2[1]+r2[2]+r2[3];
  float mu=s*(1.f/DM);
  float rstd=rsqrtf(ss*(1.f/DM)-mu*mu+1e-5f);
  float4 gv=((const float4*)g)[tid], bv=((const float4*)be)[tid];
  float4 o;
  o.x=(y.x-mu)*rstd*gv.x+bv.x;
  o.y=(y.y-mu)*rstd*gv.y+bv.y;
  o.z=(y.z-mu)*rstd*gv.z+bv.z;
  o.w=(y.w-mu)*rstd*gv.w+bv.w;
  ((float4*)(out + (size_t)row*DM))[tid] = o;
}

// ---------------- cast + transpose: w[R][C] f32 -> wt[C][R] bf16 ----------------
__global__ __launch_bounds__(256) void cast_t(const float* __restrict__ w, short* __restrict__ wt, int R, int C)
{
  __shared__ short t[64][65];
  int nbr = R>>6;
  int br = (int)blockIdx.x % nbr, bc = (int)blockIdx.x / nbr;
  int tid = threadIdx.x;
  #pragma unroll
  for (int i=0;i<4;i++){
    int c = i*256 + tid;
    int r = c>>4, c4 = (c&15)*4;
    float4 v = *(const float4*)(w + (size_t)(br*64 + r)*C + bc*64 + c4);
    t[r][c4+0]=f2b(v.x); t[r][c4+1]=f2b(v.y); t[r][c4+2]=f2b(v.z); t[r][c4+3]=f2b(v.w);
  }
  __syncthreads();
  #pragma unroll
  for (int i=0;i<4;i++){
    int c = i*256 + tid;
    int oc = c>>4, c4 = (c&15)*4;
    s16x4 p;
    p[0]=t[c4+0][oc]; p[1]=t[c4+1][oc]; p[2]=t[c4+2][oc]; p[3]=t[c4+3][oc];
    *(s16x4*)&wt[(size_t)(bc*64 + oc)*R + br*64 + c4] = p;
  }
}

// ---------------- launcher ----------------
extern "C" void kernel_launch(void* const* d_in, const int* in_sizes, int n_in,
                              void* d_out, int out_size, void* d_ws, size_t ws_size,
                              hipStream_t stream)
{
  const float* x      = (const float*)d_in[0];
  const float* qkv_w  = (const float*)d_in[1];
  const float* qkv_b  = (const float*)d_in[2];
  const float* out_w  = (const float*)d_in[3];
  const float* out_b  = (const float*)d_in[4];
  const float* aln_g  = (const float*)d_in[5];
  const float* aln_b  = (const float*)d_in[6];
  const float* n1_g   = (const float*)d_in[7];
  const float* n1_b   = (const float*)d_in[8];
  const float* fln_g  = (const float*)d_in[9];
  const float* fln_b  = (const float*)d_in[10];
  const float* w1     = (const float*)d_in[11];
  const float* b1     = (const float*)d_in[12];
  const float* w2     = (const float*)d_in[13];
  const float* b2     = (const float*)d_in[14];
  const float* n2_g   = (const float*)d_in[15];
  const float* n2_b   = (const float*)d_in[16];

  char* ws = (char*)d_ws;
  short* wqkvT = (short*)(ws + 0);          // [3072][1024] bf16
  short* woutT = (short*)(ws + 6291456);    // [1024][1024]
  short* w1T   = (short*)(ws + 8388608);    // [4096][1024]
  short* w2T   = (short*)(ws + 16777216);   // [1024][4096]
  short* h1    = (short*)(ws + 25165824);   // [4096][1024] bf16 (reused as h2)
  short* qkv   = (short*)(ws + 33554432);   // [4096][3072] bf16
  float* attn_out = (float*)(ws + 33554432);// aliases qkv (dead by then)
  short* ff1   = (short*)(ws + 33554432);   // [4096][4096] bf16, aliases qkv+ctx
  short* ctx   = (short*)(ws + 58720256);   // [4096][1024] bf16
  float* x1    = (float*)(ws + 67108864);   // [4096][1024] f32
  float* ff2   = (float*)(ws + 83886080);   // [4096][1024] f32
  float* outp  = (float*)d_out;

  cast_t<<<dim3(16*48),256,0,stream>>>(qkv_w, wqkvT, 1024, 3072);
  cast_t<<<dim3(16*16),256,0,stream>>>(out_w, woutT, 1024, 1024);
  cast_t<<<dim3(16*64),256,0,stream>>>(w1,    w1T,   1024, 4096);
  cast_t<<<dim3(64*16),256,0,stream>>>(w2,    w2T,   4096, 1024);

  ln_in<<<NTOK,256,0,stream>>>(x, aln_g, aln_b, h1);
  gemm_bt<0,1><<<dim3(32*24),256,0,stream>>>(h1, wqkvT, qkv_b, qkv, 4096,3072,1024);
  attn_fwd<<<dim3(32,32),256,0,stream>>>(qkv, ctx);
  gemm_bt<0,0><<<dim3(32*8),256,0,stream>>>(ctx, woutT, out_b, attn_out, 4096,1024,1024);
  ln_chain<<<NTOK,256,0,stream>>>(x, attn_out, n1_g, n1_b, fln_g, fln_b, x1, h1);
  gemm_bt<1,1><<<dim3(32*32),256,0,stream>>>(h1, w1T, b1, ff1, 4096,4096,1024);
  gemm_bt<0,0><<<dim3(32*8),256,0,stream>>>(ff1, w2T, b2, ff2, 4096,1024,4096);
  ln_out_k<<<NTOK,256,0,stream>>>(x1, ff2, n2_g, n2_b, outp);
}

// Round 3
// 354.426 us; speedup vs baseline: 1.1475x; 1.0087x over previous
//
#include <hip/hip_runtime.h>
#include <hip/hip_bf16.h>

typedef __attribute__((ext_vector_type(4))) float f32x4;
typedef __attribute__((ext_vector_type(8))) short s16x8;
typedef __attribute__((ext_vector_type(4))) short s16x4;

#define DM 1024
#define NH 16
#define NB 2
#define NS 2048
#define NTOK (NB*NS)

__device__ __forceinline__ float b2f(short u){
  union { unsigned int i; float f; } c; c.i = ((unsigned int)(unsigned short)u) << 16; return c.f;
}
__device__ __forceinline__ short f2b(float f){
  __hip_bfloat16 h = __float2bfloat16(f);
  return __builtin_bit_cast(short, h);
}
__device__ __forceinline__ void gload16(const void* g, void* l){
  __builtin_amdgcn_global_load_lds((const __attribute__((address_space(1))) void*)g,
                                   (__attribute__((address_space(3))) void*)l, 16, 0, 0);
}
// hardware transpose read: lane l gets elems base_e + (l&15) + j*16 + (l>>4)*64
__device__ __forceinline__ s16x4 tr16(const void* p){
  s16x4 r;
  asm volatile("ds_read_b64_tr_b16 %0, %1"
               : "=v"(r)
               : "v"((const __attribute__((address_space(3))) short*)p)
               : "memory");
  return r;
}

// ======== 256x256 tile, BK=32, 4-deep counted-vmcnt pipeline (T2+T4+T5) ========
// LDS layout per tile buffer: 16 subtiles (rs=row>>4) of 16 rows x 32 k, 1024B each.
//   byte(row,k) = (row>>4)*1024 + (row&15)*64 + ((k*2) ^ (((row>>3)&1)<<5))   [st_16x32 swizzle]
// gload_lds (width16) writes one subtile per wave-instruction: lane l -> byte l*16.
//   source for lane l: row = rs*16 + (l>>2), k-byte = ((l&3)*16) ^ (l&32)   [pre-swizzled src]
// Schedule per K-step: vmcnt(8) [tiles t+1,t+2 in flight]; s_barrier; stage t+3; ds_read t; 32 MFMA.
template<int GELU>
__global__ __launch_bounds__(512,2) void gemm256(
    const short* __restrict__ A, const short* __restrict__ Bt,
    const float* __restrict__ bias, short* __restrict__ C,
    int M, int N, int K)
{
  __shared__ short Al[4*8192];
  __shared__ short Bl[4*8192];
  int tid = threadIdx.x, wid = tid>>6, lane = tid&63;
  int la = lane&15, lb = lane>>4;
  int nbn = N>>8;
  int nwg = (M>>8)*nbn;
  int bid = (int)blockIdx.x;
  int sid = (bid&7)*(nwg>>3) + (bid>>3);      // bijective XCD swizzle (nwg%8==0)
  int bm = sid / nbn, bn = sid % nbn;
  int wm = (wid>>2)*128, wn = (wid&3)*64;

  // per-lane staging source constants
  int srow = lane>>2;
  int skb  = ((lane&3)*16) ^ (lane&32);       // byte offset in k (pre-swizzled)
  const short* Abase = A  + (size_t)(bm*256 + srow)*K + (skb>>1);
  const short* Bbase = Bt + (size_t)(bn*256 + srow)*K + (skb>>1);

  auto stage = [&](int tt){
    int buf = tt&3;
    int kt = tt<<5;
    short* Ad = &Al[buf*8192];
    short* Bd = &Bl[buf*8192];
    gload16(Abase + (size_t)(wid*16)*K     + kt, Ad + wid*512);
    gload16(Abase + (size_t)((wid+8)*16)*K + kt, Ad + (wid+8)*512);
    gload16(Bbase + (size_t)(wid*16)*K     + kt, Bd + wid*512);
    gload16(Bbase + (size_t)((wid+8)*16)*K + kt, Bd + (wid+8)*512);
  };

  int NT = K>>5;
  stage(0); stage(1); stage(2);

  f32x4 acc[8][4] = {};
  int foff = la*32 + (((lb*16) ^ ((la&8)<<2))>>1);   // shorts, within subtile
  int aoff = ((wm>>4)<<9) + foff;
  int boff = ((wn>>4)<<9) + foff;

  for (int t=0; t<NT; t++){
    __builtin_amdgcn_sched_barrier(0);
    if (t+2 < NT)      asm volatile("s_waitcnt vmcnt(8)" ::: "memory");
    else if (t+1 < NT) asm volatile("s_waitcnt vmcnt(4)" ::: "memory");
    else               asm volatile("s_waitcnt vmcnt(0)" ::: "memory");
    __builtin_amdgcn_s_barrier();
    __builtin_amdgcn_sched_barrier(0);
    if (t+3 < NT) stage(t+3);
    int buf = t&3;
    const short* Ab = &Al[buf*8192];
    const short* Bb = &Bl[buf*8192];
    s16x8 af[8], bfr[4];
    #pragma unroll
    for (int mi=0;mi<8;mi++) af[mi]  = *(const s16x8*)(Ab + aoff + mi*512);
    #pragma unroll
    for (int ni=0;ni<4;ni++) bfr[ni] = *(const s16x8*)(Bb + boff + ni*512);
    __builtin_amdgcn_s_setprio(1);
    #pragma unroll
    for (int mi=0;mi<8;mi++)
      #pragma unroll
      for (int ni=0;ni<4;ni++)
        acc[mi][ni] = __builtin_amdgcn_mfma_f32_16x16x32_bf16(af[mi], bfr[ni], acc[mi][ni], 0,0,0);
    __builtin_amdgcn_s_setprio(0);
  }

  #pragma unroll
  for (int ni=0;ni<4;ni++){
    int col = bn*256 + wn + ni*16 + la;
    float bv = bias[col];
    #pragma unroll
    for (int mi=0;mi<8;mi++){
      int row0 = bm*256 + wm + mi*16 + lb*4;
      #pragma unroll
      for (int j=0;j<4;j++){
        float v = acc[mi][ni][j] + bv;
        if (GELU) v = 0.5f*v*(1.0f + erff(v*0.70710678118f));
        C[(size_t)(row0+j)*N + col] = f2b(v);
      }
    }
  }
}

// ---------------- GEMM: C[M,N] = A[M,K](bf16) * Bt[N,K](bf16)^T + bias ----------------
template<int GELU, int OUTBF16>
__global__ __launch_bounds__(256,2) void gemm_bt(
    const short* __restrict__ A, const short* __restrict__ Bt,
    const float* __restrict__ bias, void* __restrict__ Cv,
    int M, int N, int K)
{
  __shared__ short Al[128*64];
  __shared__ short Bl[128*64];
  int tid = threadIdx.x, wid = tid>>6, lane = tid&63;
  int la = lane&15, lb = lane>>4;
  int nbn = N>>7;
  int nwg = (M>>7)*nbn;
  int bid = (int)blockIdx.x;
  int sid = ((nwg&7)==0) ? ((bid&7)*(nwg>>3) + (bid>>3)) : bid;
  int bm = sid / nbn, bn = sid % nbn;
  int wm = (wid>>1)<<6, wn = (wid&1)<<6;
  f32x4 acc[4][4] = {};
  for (int kt=0; kt<K; kt+=64){
    #pragma unroll
    for (int i=0;i<4;i++){
      int c = i*256+tid; int r=c>>3, col=(c&7)<<3;
      gload16(A + (size_t)(bm*128+r)*K + kt + col, &Al[(i*256+wid*64)*8]);
    }
    #pragma unroll
    for (int i=0;i<4;i++){
      int c = i*256+tid; int r=c>>3, col=(c&7)<<3;
      gload16(Bt + (size_t)(bn*128+r)*K + kt + col, &Bl[(i*256+wid*64)*8]);
    }
    __syncthreads();
    #pragma unroll
    for (int ks=0;ks<64;ks+=32){
      s16x8 af[4], bfr[4];
      #pragma unroll
      for (int mi=0;mi<4;mi++) af[mi]  = *(const s16x8*)&Al[(wm+mi*16+la)*64 + ks + lb*8];
      #pragma unroll
      for (int ni=0;ni<4;ni++) bfr[ni] = *(const s16x8*)&Bl[(wn+ni*16+la)*64 + ks + lb*8];
      #pragma unroll
      for (int mi=0;mi<4;mi++)
        #pragma unroll
        for (int ni=0;ni<4;ni++)
          acc[mi][ni] = __builtin_amdgcn_mfma_f32_16x16x32_bf16(af[mi], bfr[ni], acc[mi][ni], 0,0,0);
    }
    __syncthreads();
  }
  #pragma unroll
  for (int ni=0;ni<4;ni++){
    int col = bn*128 + wn + ni*16 + la;
    float bv = bias[col];
    #pragma unroll
    for (int mi=0;mi<4;mi++){
      int row0 = bm*128 + wm + mi*16 + lb*4;
      #pragma unroll
      for (int j=0;j<4;j++){
        float v = acc[mi][ni][j] + bv;
        if (GELU) v = 0.5f*v*(1.0f + erff(v*0.70710678118f));
        if (OUTBF16) ((short*)Cv)[(size_t)(row0+j)*N + col] = f2b(v);
        else ((float*)Cv)[(size_t)(row0+j)*N + col] = v;
      }
    }
  }
}

// ---------------- Flash attention: qkv bf16 [NTOK,3*DM] -> ctx bf16 [NTOK,DM] ----------------
__global__ __launch_bounds__(256,3) void attn_fwd(const short* __restrict__ qkv, short* __restrict__ ctx)
{
  __shared__ short Kl[2][4096];
  __shared__ short Vl[2][4096];
  __shared__ short Pl[4608];          // 4 waves x [16][72]
  int tid=threadIdx.x, wid=tid>>6, lane=tid&63;
  int la = lane&15, lb = lane>>4;
  int qt = blockIdx.x, bh = blockIdx.y;
  int b = bh>>4, h = bh&15;
  int q0 = qt*64 + wid*16;

  const size_t qrow = (size_t)(b*NS + q0 + la)*3072 + h*64 + lb*8;
  s16x8 qf0 = *(const s16x8*)(qkv + qrow);
  s16x8 qf1 = *(const s16x8*)(qkv + qrow + 32);
  #pragma unroll
  for (int i=0;i<8;i++){ qf0[i] = f2b(b2f(qf0[i])*0.125f); qf1[i] = f2b(b2f(qf1[i])*0.125f); }

  f32x4 cacc[4] = {};
  float mrow[4] = {-1e30f,-1e30f,-1e30f,-1e30f};
  float lrow[4] = {0.f,0.f,0.f,0.f};

  auto stage = [&](int t, int bf){
    #pragma unroll
    for (int i=0;i<2;i++){
      int p = (i*256 + tid)*16;
      int row = p>>7, inner = p&127;
      int srcb = inner ^ ((row&7)<<4);
      const short* src = qkv + (size_t)(b*NS + t*64 + row)*3072 + h*64 + 1024 + (srcb>>1);
      gload16(src, (char*)&Kl[bf][0] + (i*256 + wid*64)*16);
    }
    #pragma unroll
    for (int i=0;i<2;i++){
      int e = (i*256 + tid)*8;
      int dd = e>>10, kh=(e>>9)&1, kb3=(e>>6)&7, kj=(e>>4)&3, dlo=e&15;
      int k = kb3*8 + kh*4 + kj, d = dd*16 + dlo;
      const short* src = qkv + (size_t)(b*NS + t*64 + k)*3072 + h*64 + 2048 + d;
      gload16(src, (char*)&Vl[bf][0] + (i*256 + wid*64)*16);
    }
  };

  stage(0, 0);
  __syncthreads();
  int cur = 0;

  for (int t=0; t<NS/64; t++){
    if (t+1 < NS/64) stage(t+1, cur^1);

    const char* Kb = (const char*)&Kl[cur][0];
    f32x4 sacc[4] = {};
    #pragma unroll
    for (int nk=0;nk<4;nk++){
      int r = nk*16+la;
      int sw = (r&7)<<4;
      s16x8 kf0 = *(const s16x8*)(Kb + r*128 + ((lb*16) ^ sw));
      s16x8 kf1 = *(const s16x8*)(Kb + r*128 + ((64 + lb*16) ^ sw));
      sacc[nk] = __builtin_amdgcn_mfma_f32_16x16x32_bf16(qf0, kf0, sacc[nk], 0,0,0);
      sacc[nk] = __builtin_amdgcn_mfma_f32_16x16x32_bf16(qf1, kf1, sacc[nk], 0,0,0);
    }

    float tloc[4];
    #pragma unroll
    for (int j=0;j<4;j++)
      tloc[j] = fmaxf(fmaxf(sacc[0][j],sacc[1][j]),fmaxf(sacc[2][j],sacc[3][j]));
    float excess = fmaxf(fmaxf(tloc[0]-mrow[0],tloc[1]-mrow[1]),
                         fmaxf(tloc[2]-mrow[2],tloc[3]-mrow[3]));
    if (__any(excess > 8.f)){
      #pragma unroll
      for (int j=0;j<4;j++){
        float tm = tloc[j];
        tm = fmaxf(tm, __shfl_xor(tm,1,64));
        tm = fmaxf(tm, __shfl_xor(tm,2,64));
        tm = fmaxf(tm, __shfl_xor(tm,4,64));
        tm = fmaxf(tm, __shfl_xor(tm,8,64));
        float mn = fmaxf(mrow[j], tm);
        float c = __expf(mrow[j]-mn);
        mrow[j] = mn; lrow[j] *= c;
        #pragma unroll
        for (int nd=0;nd<4;nd++) cacc[nd][j] *= c;
      }
    }
    #pragma unroll
    for (int j=0;j<4;j++){
      float rs = 0.f;
      #pragma unroll
      for (int nk=0;nk<4;nk++){ float p = __expf(sacc[nk][j]-mrow[j]); sacc[nk][j]=p; rs += p; }
      rs += __shfl_xor(rs,1,64); rs += __shfl_xor(rs,2,64);
      rs += __shfl_xor(rs,4,64); rs += __shfl_xor(rs,8,64);
      lrow[j] += rs;
    }

    #pragma unroll
    for (int nk=0;nk<4;nk++)
      #pragma unroll
      for (int j=0;j<4;j++)
        Pl[wid*1152 + (lb*4+j)*72 + la + 16*nk] = f2b(sacc[nk][j]);
    s16x8 pf0 = *(const s16x8*)&Pl[wid*1152 + la*72 + lb*8];
    s16x8 pf1 = *(const s16x8*)&Pl[wid*1152 + la*72 + 32 + lb*8];

    const char* Vb = (const char*)&Vl[cur][0];
    s16x4 tv[4][4];
    #pragma unroll
    for (int nd=0;nd<4;nd++)
      #pragma unroll
      for (int q=0;q<4;q++){
        int ks = q>>1, jh = q&1;
        tv[nd][q] = tr16(Vb + nd*2048 + jh*1024 + ks*512 + lane*8);
      }
    asm volatile("s_waitcnt lgkmcnt(0)" ::: "memory");
    __builtin_amdgcn_sched_barrier(0);

    #pragma unroll
    for (int nd=0;nd<4;nd++){
      union { s16x4 h[2]; s16x8 v; } u0, u1;
      u0.h[0]=tv[nd][0]; u0.h[1]=tv[nd][1];
      u1.h[0]=tv[nd][2]; u1.h[1]=tv[nd][3];
      cacc[nd] = __builtin_amdgcn_mfma_f32_16x16x32_bf16(pf0, u0.v, cacc[nd], 0,0,0);
      cacc[nd] = __builtin_amdgcn_mfma_f32_16x16x32_bf16(pf1, u1.v, cacc[nd], 0,0,0);
    }

    __syncthreads();
    cur ^= 1;
  }

  #pragma unroll
  for (int nd=0;nd<4;nd++){
    int dcol = h*64 + nd*16 + la;
    #pragma unroll
    for (int j=0;j<4;j++){
      int row = b*NS + q0 + lb*4 + j;
      ctx[(size_t)row*DM + dcol] = f2b(cacc[nd][j] / lrow[j]);
    }
  }
}

// ---------------- LayerNorm kernels ----------------
__device__ __forceinline__ void wred2(float& s, float& ss){
  #pragma unroll
  for (int m=1;m<64;m<<=1){ s += __shfl_xor(s,m,64); ss += __shfl_xor(ss,m,64); }
}

__global__ __launch_bounds__(256) void ln_in(const float* __restrict__ x,
    const float* __restrict__ g, const float* __restrict__ be, short* __restrict__ out)
{
  int row=blockIdx.x, tid=threadIdx.x;
  __shared__ float r1[4], r2[4];
  float4 v = ((const float4*)(x + (size_t)row*DM))[tid];
  float s=v.x+v.y+v.z+v.w, ss=v.x*v.x+v.y*v.y+v.z*v.z+v.w*v.w;
  wred2(s,ss);
  if ((tid&63)==0){ r1[tid>>6]=s; r2[tid>>6]=ss; }
  __syncthreads();
  s=r1[0]+r1[1]+r1[2]+r1[3]; ss=r2[0]+r2[1]+r2[2]+r2[3];
  float mu=s*(1.f/DM);
  float rstd=rsqrtf(ss*(1.f/DM)-mu*mu+1e-5f);
  float4 gv=((const float4*)g)[tid], bv=((const float4*)be)[tid];
  s16x4 o;
  o[0]=f2b((v.x-mu)*rstd*gv.x+bv.x);
  o[1]=f2b((v.y-mu)*rstd*gv.y+bv.y);
  o[2]=f2b((v.z-mu)*rstd*gv.z+bv.z);
  o[3]=f2b((v.w-mu)*rstd*gv.w+bv.w);
  *(s16x4*)(out + (size_t)row*DM + tid*4) = o;
}

__global__ __launch_bounds__(256) void ln_chain(const float* __restrict__ x, const float* __restrict__ ao,
    const float* __restrict__ g1, const float* __restrict__ be1,
    const float* __restrict__ g2, const float* __restrict__ be2,
    float* __restrict__ x1, short* __restrict__ h2)
{
  int row=blockIdx.x, tid=threadIdx.x;
  __shared__ float r1[4], r2[4], r3[4], r4[4];
  float4 xv = ((const float4*)(x + (size_t)row*DM))[tid];
  float4 av = ((const float4*)(ao + (size_t)row*DM))[tid];
  float4 y; y.x=xv.x+av.x; y.y=xv.y+av.y; y.z=xv.z+av.z; y.w=xv.w+av.w;
  float s=y.x+y.y+y.z+y.w, ss=y.x*y.x+y.y*y.y+y.z*y.z+y.w*y.w;
  wred2(s,ss);
  if ((tid&63)==0){ r1[tid>>6]=s; r2[tid>>6]=ss; }
  __syncthreads();
  s=r1[0]+r1[1]+r1[2]+r1[3]; ss=r2[0]+r2[1]+r2[2]+r2[3];
  float mu=s*(1.f/DM);
  float rstd=rsqrtf(ss*(1.f/DM)-mu*mu+1e-5f);
  float4 g1v=((const float4*)g1)[tid], b1v=((const float4*)be1)[tid];
  float4 xo;
  xo.x=(y.x-mu)*rstd*g1v.x+b1v.x;
  xo.y=(y.y-mu)*rstd*g1v.y+b1v.y;
  xo.z=(y.z-mu)*rstd*g1v.z+b1v.z;
  xo.w=(y.w-mu)*rstd*g1v.w+b1v.w;
  ((float4*)(x1 + (size_t)row*DM))[tid] = xo;
  float s2=xo.x+xo.y+xo.z+xo.w, ss2=xo.x*xo.x+xo.y*xo.y+xo.z*xo.z+xo.w*xo.w;
  wred2(s2,ss2);
  if ((tid&63)==0){ r3[tid>>6]=s2; r4[tid>>6]=ss2; }
  __syncthreads();
  s2=r3[0]+r3[1]+r3[2]+r3[3]; ss2=r4[0]+r4[1]+r4[2]+r4[3];
  float mu2=s2*(1.f/DM);
  float rstd2=rsqrtf(ss2*(1.f/DM)-mu2*mu2+1e-5f);
  float4 g2v=((const float4*)g2)[tid], b2v=((const float4*)be2)[tid];
  s16x4 o;
  o[0]=f2b((xo.x-mu2)*rstd2*g2v.x+b2v.x);
  o[1]=f2b((xo.y-mu2)*rstd2*g2v.y+b2v.y);
  o[2]=f2b((xo.z-mu2)*rstd2*g2v.z+b2v.z);
  o[3]=f2b((xo.w-mu2)*rstd2*g2v.w+b2v.w);
  *(s16x4*)(h2 + (size_t)row*DM + tid*4) = o;
}

__global__ __launch_bounds__(256) void ln_out_k(const float* __restrict__ a, const float* __restrict__ bsrc,
    const float* __restrict__ g, const float* __restrict__ be, float* __restrict__ out)
{
  int row=blockIdx.x, tid=threadIdx.x;
  __shared__ float r1[4], r2[4];
  float4 xv = ((const float4*)(a + (size_t)row*DM))[tid];
  float4 av = ((const float4*)(bsrc + (size_t)row*DM))[tid];
  float4 y; y.x=xv.x+av.x; y.y=xv.y+av.y; y.z=xv.z+av.z; y.w=xv.w+av.w;
  float s=y.x+y.y+y.z+y.w, ss=y.x*y.x+y.y*y.y+y.z*y.z+y.w*y.w;
  wred2(s,ss);
  if ((tid&63)==0){ r1[tid>>6]=s; r2[tid>>6]=ss; }
  __syncthreads();
  s=r1[0]+r1[1]+r1[2]+r1[3]; ss=r2[0]+r2[1]+r2[2]+r2[3];
  float mu=s*(1.f/DM);
  float rstd=rsqrtf(ss*(1.f/DM)-mu*mu+1e-5f);
  float4 gv=((const float4*)g)[tid], bv=((const float4*)be)[tid];
  float4 o;
  o.x=(y.x-mu)*rstd*gv.x+bv.x;
  o.y=(y.y-mu)*rstd*gv.y+bv.y;
  o.z=(y.z-mu)*rstd*gv.z+bv.z;
  o.w=(y.w-mu)*rstd*gv.w+bv.w;
  ((float4*)(out + (size_t)row*DM))[tid] = o;
}

// ---------------- cast + transpose: w[R][C] f32 -> wt[C][R] bf16 ----------------
__global__ __launch_bounds__(256) void cast_t(const float* __restrict__ w, short* __restrict__ wt, int R, int C)
{
  __shared__ short t[64][65];
  int nbr = R>>6;
  int br = (int)blockIdx.x % nbr, bc = (int)blockIdx.x / nbr;
  int tid = threadIdx.x;
  #pragma unroll
  for (int i=0;i<4;i++){
    int c = i*256 + tid;
    int r = c>>4, c4 = (c&15)*4;
    float4 v = *(const float4*)(w + (size_t)(br*64 + r)*C + bc*64 + c4);
    t[r][c4+0]=f2b(v.x); t[r][c4+1]=f2b(v.y); t[r][c4+2]=f2b(v.z); t[r][c4+3]=f2b(v.w);
  }
  __syncthreads();
  #pragma unroll
  for (int i=0;i<4;i++){
    int c = i*256 + tid;
    int oc = c>>4, c4 = (c&15)*4;
    s16x4 p;
    p[0]=t[c4+0][oc]; p[1]=t[c4+1][oc]; p[2]=t[c4+2][oc]; p[3]=t[c4+3][oc];
    *(s16x4*)&wt[(size_t)(bc*64 + oc)*R + br*64 + c4] = p;
  }
}

// ---------------- launcher ----------------
extern "C" void kernel_launch(void* const* d_in, const int* in_sizes, int n_in,
                              void* d_out, int out_size, void* d_ws, size_t ws_size,
                              hipStream_t stream)
{
  const float* x      = (const float*)d_in[0];
  const float* qkv_w  = (const float*)d_in[1];
  const float* qkv_b  = (const float*)d_in[2];
  const float* out_w  = (const float*)d_in[3];
  const float* out_b  = (const float*)d_in[4];
  const float* aln_g  = (const float*)d_in[5];
  const float* aln_b  = (const float*)d_in[6];
  const float* n1_g   = (const float*)d_in[7];
  const float* n1_b   = (const float*)d_in[8];
  const float* fln_g  = (const float*)d_in[9];
  const float* fln_b  = (const float*)d_in[10];
  const float* w1     = (const float*)d_in[11];
  const float* b1     = (const float*)d_in[12];
  const float* w2     = (const float*)d_in[13];
  const float* b2     = (const float*)d_in[14];
  const float* n2_g   = (const float*)d_in[15];
  const float* n2_b   = (const float*)d_in[16];

  char* ws = (char*)d_ws;
  short* wqkvT = (short*)(ws + 0);          // [3072][1024] bf16
  short* woutT = (short*)(ws + 6291456);    // [1024][1024]
  short* w1T   = (short*)(ws + 8388608);    // [4096][1024]
  short* w2T   = (short*)(ws + 16777216);   // [1024][4096]
  short* h1    = (short*)(ws + 25165824);   // [4096][1024] bf16 (reused as h2)
  short* qkv   = (short*)(ws + 33554432);   // [4096][3072] bf16
  float* attn_out = (float*)(ws + 33554432);// aliases qkv (dead by then)
  short* ff1   = (short*)(ws + 33554432);   // [4096][4096] bf16, aliases qkv+ctx
  short* ctx   = (short*)(ws + 58720256);   // [4096][1024] bf16
  float* x1    = (float*)(ws + 67108864);   // [4096][1024] f32
  float* ff2   = (float*)(ws + 83886080);   // [4096][1024] f32
  float* outp  = (float*)d_out;

  cast_t<<<dim3(16*48),256,0,stream>>>(qkv_w, wqkvT, 1024, 3072);
  cast_t<<<dim3(16*16),256,0,stream>>>(out_w, woutT, 1024, 1024);
  cast_t<<<dim3(16*64),256,0,stream>>>(w1,    w1T,   1024, 4096);
  cast_t<<<dim3(64*16),256,0,stream>>>(w2,    w2T,   4096, 1024);

  ln_in<<<NTOK,256,0,stream>>>(x, aln_g, aln_b, h1);
  gemm256<0><<<dim3(16*12),512,0,stream>>>(h1, wqkvT, qkv_b, qkv, 4096,3072,1024);
  attn_fwd<<<dim3(32,32),256,0,stream>>>(qkv, ctx);
  gemm_bt<0,0><<<dim3(32*8),256,0,stream>>>(ctx, woutT, out_b, attn_out, 4096,1024,1024);
  ln_chain<<<NTOK,256,0,stream>>>(x, attn_out, n1_g, n1_b, fln_g, fln_b, x1, h1);
  gemm256<1><<<dim3(16*16),512,0,stream>>>(h1, w1T, b1, ff1, 4096,4096,1024);
  gemm_bt<0,0><<<dim3(32*8),256,0,stream>>>(ff1, w2T, b2, ff2, 4096,1024,4096);
  ln_out_k<<<NTOK,256,0,stream>>>(x1, ff2, n2_g, n2_b, outp);
}

// Round 4
// 339.795 us; speedup vs baseline: 1.1969x; 1.0431x over previous
//
#include <hip/hip_runtime.h>
#include <hip/hip_bf16.h>

typedef __attribute__((ext_vector_type(4))) float f32x4;
typedef __attribute__((ext_vector_type(8))) short s16x8;
typedef __attribute__((ext_vector_type(4))) short s16x4;

#define DM 1024
#define NH 16
#define NB 2
#define NS 2048
#define NTOK (NB*NS)

__device__ __forceinline__ float b2f(short u){
  union { unsigned int i; float f; } c; c.i = ((unsigned int)(unsigned short)u) << 16; return c.f;
}
__device__ __forceinline__ short f2b(float f){
  __hip_bfloat16 h = __float2bfloat16(f);
  return __builtin_bit_cast(short, h);
}
__device__ __forceinline__ void gload16(const void* g, void* l){
  __builtin_amdgcn_global_load_lds((const __attribute__((address_space(1))) void*)g,
                                   (__attribute__((address_space(3))) void*)l, 16, 0, 0);
}
__device__ __forceinline__ s16x4 tr16(const void* p){
  s16x4 r;
  asm volatile("ds_read_b64_tr_b16 %0, %1"
               : "=v"(r)
               : "v"((const __attribute__((address_space(3))) short*)p)
               : "memory");
  return r;
}

#define BARX { __builtin_amdgcn_sched_barrier(0); __builtin_amdgcn_s_barrier(); __builtin_amdgcn_sched_barrier(0); }
#define LGK  { asm volatile("s_waitcnt lgkmcnt(0)" ::: "memory"); __builtin_amdgcn_sched_barrier(0); }

// ======== 256x256 8-phase GEMM (T1+T2+T3+T4+T5), BK=64, 2 K-tiles/iter ========
// LDS per K-tile buffer: A 256x64 bf16 (32KB) + B 256x64 (32KB); 2 buffers = 128KB.
// Subtile = 16 rows x 32 k x 2B = 1024B; addr(row,k) = (row>>4)*2048 + (k>>5)*1024
//   + (row&15)*64 + ((k&31)*2 ^ (((row>>3)&1)<<5))   [st_16x32: byte ^= ((byte>>9)&1)<<5]
// Stage: per wave-call 1KB subtile, lane l -> byte l*16; source pre-swizzled so layout above holds.
template<int MIH>
__device__ __forceinline__ void rdA(s16x8 (&Af)[4][2], const short* Ab, int foff){
  #pragma unroll
  for (int m=0;m<4;m++)
    #pragma unroll
    for (int ks=0;ks<2;ks++)
      Af[m][ks] = *(const s16x8*)(Ab + (MIH*4+m)*1024 + ks*512 + foff);
}
template<int NIH>
__device__ __forceinline__ void rdB(s16x8 (&Bf)[4][2], const short* Bb, int foff){
  #pragma unroll
  for (int n=0;n<2;n++)
    #pragma unroll
    for (int ks=0;ks<2;ks++)
      Bf[NIH*2+n][ks] = *(const s16x8*)(Bb + (NIH*2+n)*1024 + ks*512 + foff);
}
template<int MIH,int NIH>
__device__ __forceinline__ void mmQ(f32x4 (&acc)[8][4], s16x8 (&Af)[4][2], s16x8 (&Bf)[4][2]){
  __builtin_amdgcn_s_setprio(1);
  #pragma unroll
  for (int m=0;m<4;m++)
    #pragma unroll
    for (int n=0;n<2;n++)
      #pragma unroll
      for (int ks=0;ks<2;ks++)
        acc[MIH*4+m][NIH*2+n] = __builtin_amdgcn_mfma_f32_16x16x32_bf16(
            Af[m][ks], Bf[NIH*2+n][ks], acc[MIH*4+m][NIH*2+n], 0,0,0);
  __builtin_amdgcn_s_setprio(0);
}

template<int GELU>
__global__ __launch_bounds__(512,2) void gemm8p(
    const short* __restrict__ A, const short* __restrict__ Bt,
    const float* __restrict__ bias, short* __restrict__ C,
    int M, int N, int K)
{
  __shared__ short Al[2*16384];
  __shared__ short Bl[2*16384];
  int tid = threadIdx.x, wid = tid>>6, lane = tid&63;
  int la = lane&15, lb = lane>>4;
  int nbn = N>>8;
  int nwg = (M>>8)*nbn;
  int bid = (int)blockIdx.x;
  int sid = (bid&7)*(nwg>>3) + (bid>>3);      // bijective XCD swizzle (nwg%8==0)
  int bm = sid / nbn, bn = sid % nbn;
  int wm2 = wid>>2, wn4 = wid&3;              // 2M x 4N waves; wave tile 128x64
  int bhalf = wn4>>1, bq4 = (wn4&1)*4;

  const short* aA0 = A  + (size_t)(bm*256)*K;
  const short* aA1 = A  + (size_t)(bm*256+128)*K;
  const short* bB0 = Bt + (size_t)(bn*256)*K;
  const short* bB1 = Bt + (size_t)(bn*256+128)*K;

  // stage one 16KB half-tile (2 wave-calls x 8 subtiles)
  auto stG = [&](short* dstHalf, const short* srcRow0, int kt){
    #pragma unroll
    for (int c=0;c<2;c++){
      int s = c*8 + wid;                                  // subtile 0..15
      int row = ((s>>1)<<4) + (lane>>2);
      int kk  = kt + ((s&1)<<5) + (((lane&3)<<3) ^ ((lane&32)>>1));
      gload16(srcRow0 + (size_t)row*K + kk, dstHalf + s*512);
    }
  };

  int NJ = K>>7;                               // iters; 2 K-tiles (BK=64) each
  // prologue: buf0 <- tile0 (A+B), buf1.B <- tile1
  stG(&Al[0], aA0, 0);      stG(&Al[8192], aA1, 0);
  stG(&Bl[0], bB0, 0);      stG(&Bl[8192], bB1, 0);
  stG(&Bl[16384], bB0, 64); stG(&Bl[16384+8192], bB1, 64);
  asm volatile("s_waitcnt vmcnt(4)" ::: "memory");
  BARX;

  f32x4 acc[8][4] = {};
  s16x8 Af[4][2], Bf[4][2];
  int foff = la*32 + ((lb*8) ^ ((la&8)<<1));   // shorts, within subtile

  const short* Ab0c = &Al[wm2*8192];
  const short* Ab1c = &Al[16384 + wm2*8192];
  const short* Bb0c = &Bl[bhalf*8192 + bq4*1024];
  const short* Bb1c = &Bl[16384 + bhalf*8192 + bq4*1024];

  for (int j=0;j<NJ;j++){
    bool more = (j+1 < NJ);
    int ktA  = (2*j+1)*64;                     // buf1.A source (tile t1, read ph5/ph7)
    int ktN0 = (2*j+2)*64, ktN1 = (2*j+3)*64;  // next tiles
    // ---- ph1: reads buf0 A[0-3]+B[0-1]; stage buf1.A0<-t1 ----
    rdA<0>(Af, Ab0c, foff); rdB<0>(Bf, Bb0c, foff);
    stG(&Al[16384], aA0, ktA);
    BARX; LGK; mmQ<0,0>(acc,Af,Bf); BARX;
    // ---- ph2: reads B[2-3]; stage buf1.A1<-t1 ----
    rdB<1>(Bf, Bb0c, foff);
    stG(&Al[16384+8192], aA1, ktA);
    BARX; LGK; mmQ<0,1>(acc,Af,Bf); BARX;
    // ---- ph3: reads A[4-7]; stage buf0.B0<-t0+2 ----
    rdA<1>(Af, Ab0c, foff);
    if (more) stG(&Bl[0], bB0, ktN0);
    BARX; LGK; mmQ<1,1>(acc,Af,Bf); BARX;
    // ---- ph4: stage buf0.B1<-t0+2; vmcnt(4) ----
    if (more){ stG(&Bl[8192], bB1, ktN0);
               asm volatile("s_waitcnt vmcnt(4)" ::: "memory"); }
    else     { asm volatile("s_waitcnt vmcnt(0)" ::: "memory"); }
    BARX; mmQ<1,0>(acc,Af,Bf); BARX;
    // ---- ph5: reads buf1 A[0-3]+B[0-1]; stage buf0.A0<-t0+2 ----
    rdA<0>(Af, Ab1c, foff); rdB<0>(Bf, Bb1c, foff);
    if (more) stG(&Al[0], aA0, ktN0);
    BARX; LGK; mmQ<0,0>(acc,Af,Bf); BARX;
    // ---- ph6: reads B[2-3]; stage buf0.A1<-t0+2 ----
    rdB<1>(Bf, Bb1c, foff);
    if (more) stG(&Al[8192], aA1, ktN0);
    BARX; LGK; mmQ<0,1>(acc,Af,Bf); BARX;
    // ---- ph7: reads A[4-7]; stage buf1.B0<-t1+2 ----
    rdA<1>(Af, Ab1c, foff);
    if (more) stG(&Bl[16384], bB0, ktN1);
    BARX; LGK; mmQ<1,1>(acc,Af,Bf); BARX;
    // ---- ph8: stage buf1.B1<-t1+2; vmcnt(4) ----
    if (more){ stG(&Bl[16384+8192], bB1, ktN1);
               asm volatile("s_waitcnt vmcnt(4)" ::: "memory"); }
    else     { asm volatile("s_waitcnt vmcnt(0)" ::: "memory"); }
    BARX; mmQ<1,0>(acc,Af,Bf); BARX;
  }

  #pragma unroll
  for (int ni=0;ni<4;ni++){
    int col = bn*256 + wn4*64 + ni*16 + la;
    float bv = bias[col];
    #pragma unroll
    for (int mi=0;mi<8;mi++){
      int row0 = bm*256 + wm2*128 + mi*16 + lb*4;
      #pragma unroll
      for (int j=0;j<4;j++){
        float v = acc[mi][ni][j] + bv;
        if (GELU) v = 0.5f*v*(1.0f + erff(v*0.70710678118f));
        C[(size_t)(row0+j)*N + col] = f2b(v);
      }
    }
  }
}

// ---------------- GEMM: C[M,N] = A[M,K](bf16) * Bt[N,K](bf16)^T + bias ----------------
template<int GELU, int OUTBF16>
__global__ __launch_bounds__(256,2) void gemm_bt(
    const short* __restrict__ A, const short* __restrict__ Bt,
    const float* __restrict__ bias, void* __restrict__ Cv,
    int M, int N, int K)
{
  __shared__ short Al[128*64];
  __shared__ short Bl[128*64];
  int tid = threadIdx.x, wid = tid>>6, lane = tid&63;
  int la = lane&15, lb = lane>>4;
  int nbn = N>>7;
  int nwg = (M>>7)*nbn;
  int bid = (int)blockIdx.x;
  int sid = ((nwg&7)==0) ? ((bid&7)*(nwg>>3) + (bid>>3)) : bid;
  int bm = sid / nbn, bn = sid % nbn;
  int wm = (wid>>1)<<6, wn = (wid&1)<<6;
  f32x4 acc[4][4] = {};
  for (int kt=0; kt<K; kt+=64){
    #pragma unroll
    for (int i=0;i<4;i++){
      int c = i*256+tid; int r=c>>3, col=(c&7)<<3;
      gload16(A + (size_t)(bm*128+r)*K + kt + col, &Al[(i*256+wid*64)*8]);
    }
    #pragma unroll
    for (int i=0;i<4;i++){
      int c = i*256+tid; int r=c>>3, col=(c&7)<<3;
      gload16(Bt + (size_t)(bn*128+r)*K + kt + col, &Bl[(i*256+wid*64)*8]);
    }
    __syncthreads();
    #pragma unroll
    for (int ks=0;ks<64;ks+=32){
      s16x8 af[4], bfr[4];
      #pragma unroll
      for (int mi=0;mi<4;mi++) af[mi]  = *(const s16x8*)&Al[(wm+mi*16+la)*64 + ks + lb*8];
      #pragma unroll
      for (int ni=0;ni<4;ni++) bfr[ni] = *(const s16x8*)&Bl[(wn+ni*16+la)*64 + ks + lb*8];
      #pragma unroll
      for (int mi=0;mi<4;mi++)
        #pragma unroll
        for (int ni=0;ni<4;ni++)
          acc[mi][ni] = __builtin_amdgcn_mfma_f32_16x16x32_bf16(af[mi], bfr[ni], acc[mi][ni], 0,0,0);
    }
    __syncthreads();
  }
  #pragma unroll
  for (int ni=0;ni<4;ni++){
    int col = bn*128 + wn + ni*16 + la;
    float bv = bias[col];
    #pragma unroll
    for (int mi=0;mi<4;mi++){
      int row0 = bm*128 + wm + mi*16 + lb*4;
      #pragma unroll
      for (int j=0;j<4;j++){
        float v = acc[mi][ni][j] + bv;
        if (GELU) v = 0.5f*v*(1.0f + erff(v*0.70710678118f));
        if (OUTBF16) ((short*)Cv)[(size_t)(row0+j)*N + col] = f2b(v);
        else ((float*)Cv)[(size_t)(row0+j)*N + col] = v;
      }
    }
  }
}

// ---------------- Flash attention: qkv bf16 [NTOK,3*DM] -> ctx bf16 [NTOK,DM] ----------------
__global__ __launch_bounds__(256,3) void attn_fwd(const short* __restrict__ qkv, short* __restrict__ ctx)
{
  __shared__ short Kl[2][4096];
  __shared__ short Vl[2][4096];
  __shared__ short Pl[4608];          // 4 waves x [16][72]
  int tid=threadIdx.x, wid=tid>>6, lane=tid&63;
  int la = lane&15, lb = lane>>4;
  int qt = blockIdx.x, bh = blockIdx.y;
  int b = bh>>4, h = bh&15;
  int q0 = qt*64 + wid*16;

  const size_t qrow = (size_t)(b*NS + q0 + la)*3072 + h*64 + lb*8;
  s16x8 qf0 = *(const s16x8*)(qkv + qrow);
  s16x8 qf1 = *(const s16x8*)(qkv + qrow + 32);
  #pragma unroll
  for (int i=0;i<8;i++){ qf0[i] = f2b(b2f(qf0[i])*0.125f); qf1[i] = f2b(b2f(qf1[i])*0.125f); }

  f32x4 cacc[4] = {};
  float mrow[4] = {-1e30f,-1e30f,-1e30f,-1e30f};
  float lrow[4] = {0.f,0.f,0.f,0.f};

  auto stage = [&](int t, int bf){
    #pragma unroll
    for (int i=0;i<2;i++){
      int p = (i*256 + tid)*16;
      int row = p>>7, inner = p&127;
      int srcb = inner ^ ((row&7)<<4);
      const short* src = qkv + (size_t)(b*NS + t*64 + row)*3072 + h*64 + 1024 + (srcb>>1);
      gload16(src, (char*)&Kl[bf][0] + (i*256 + wid*64)*16);
    }
    #pragma unroll
    for (int i=0;i<2;i++){
      int e = (i*256 + tid)*8;
      int dd = e>>10, kh=(e>>9)&1, kb3=(e>>6)&7, kj=(e>>4)&3, dlo=e&15;
      int k = kb3*8 + kh*4 + kj, d = dd*16 + dlo;
      const short* src = qkv + (size_t)(b*NS + t*64 + k)*3072 + h*64 + 2048 + d;
      gload16(src, (char*)&Vl[bf][0] + (i*256 + wid*64)*16);
    }
  };

  stage(0, 0);
  __syncthreads();
  int cur = 0;

  for (int t=0; t<NS/64; t++){
    if (t+1 < NS/64) stage(t+1, cur^1);

    const char* Kb = (const char*)&Kl[cur][0];
    f32x4 sacc[4] = {};
    #pragma unroll
    for (int nk=0;nk<4;nk++){
      int r = nk*16+la;
      int sw = (r&7)<<4;
      s16x8 kf0 = *(const s16x8*)(Kb + r*128 + ((lb*16) ^ sw));
      s16x8 kf1 = *(const s16x8*)(Kb + r*128 + ((64 + lb*16) ^ sw));
      sacc[nk] = __builtin_amdgcn_mfma_f32_16x16x32_bf16(qf0, kf0, sacc[nk], 0,0,0);
      sacc[nk] = __builtin_amdgcn_mfma_f32_16x16x32_bf16(qf1, kf1, sacc[nk], 0,0,0);
    }

    float tloc[4];
    #pragma unroll
    for (int j=0;j<4;j++)
      tloc[j] = fmaxf(fmaxf(sacc[0][j],sacc[1][j]),fmaxf(sacc[2][j],sacc[3][j]));
    float excess = fmaxf(fmaxf(tloc[0]-mrow[0],tloc[1]-mrow[1]),
                         fmaxf(tloc[2]-mrow[2],tloc[3]-mrow[3]));
    if (__any(excess > 8.f)){
      #pragma unroll
      for (int j=0;j<4;j++){
        float tm = tloc[j];
        tm = fmaxf(tm, __shfl_xor(tm,1,64));
        tm = fmaxf(tm, __shfl_xor(tm,2,64));
        tm = fmaxf(tm, __shfl_xor(tm,4,64));
        tm = fmaxf(tm, __shfl_xor(tm,8,64));
        float mn = fmaxf(mrow[j], tm);
        float c = __expf(mrow[j]-mn);
        mrow[j] = mn; lrow[j] *= c;
        #pragma unroll
        for (int nd=0;nd<4;nd++) cacc[nd][j] *= c;
      }
    }
    #pragma unroll
    for (int j=0;j<4;j++){
      float rs = 0.f;
      #pragma unroll
      for (int nk=0;nk<4;nk++){ float p = __expf(sacc[nk][j]-mrow[j]); sacc[nk][j]=p; rs += p; }
      rs += __shfl_xor(rs,1,64); rs += __shfl_xor(rs,2,64);
      rs += __shfl_xor(rs,4,64); rs += __shfl_xor(rs,8,64);
      lrow[j] += rs;
    }

    #pragma unroll
    for (int nk=0;nk<4;nk++)
      #pragma unroll
      for (int j=0;j<4;j++)
        Pl[wid*1152 + (lb*4+j)*72 + la + 16*nk] = f2b(sacc[nk][j]);
    s16x8 pf0 = *(const s16x8*)&Pl[wid*1152 + la*72 + lb*8];
    s16x8 pf1 = *(const s16x8*)&Pl[wid*1152 + la*72 + 32 + lb*8];

    const char* Vb = (const char*)&Vl[cur][0];
    s16x4 tv[4][4];
    #pragma unroll
    for (int nd=0;nd<4;nd++)
      #pragma unroll
      for (int q=0;q<4;q++){
        int ks = q>>1, jh = q&1;
        tv[nd][q] = tr16(Vb + nd*2048 + jh*1024 + ks*512 + lane*8);
      }
    asm volatile("s_waitcnt lgkmcnt(0)" ::: "memory");
    __builtin_amdgcn_sched_barrier(0);

    #pragma unroll
    for (int nd=0;nd<4;nd++){
      union { s16x4 h[2]; s16x8 v; } u0, u1;
      u0.h[0]=tv[nd][0]; u0.h[1]=tv[nd][1];
      u1.h[0]=tv[nd][2]; u1.h[1]=tv[nd][3];
      cacc[nd] = __builtin_amdgcn_mfma_f32_16x16x32_bf16(pf0, u0.v, cacc[nd], 0,0,0);
      cacc[nd] = __builtin_amdgcn_mfma_f32_16x16x32_bf16(pf1, u1.v, cacc[nd], 0,0,0);
    }

    __syncthreads();
    cur ^= 1;
  }

  #pragma unroll
  for (int nd=0;nd<4;nd++){
    int dcol = h*64 + nd*16 + la;
    #pragma unroll
    for (int j=0;j<4;j++){
      int row = b*NS + q0 + lb*4 + j;
      ctx[(size_t)row*DM + dcol] = f2b(cacc[nd][j] / lrow[j]);
    }
  }
}

// ---------------- LayerNorm kernels ----------------
__device__ __forceinline__ void wred2(float& s, float& ss){
  #pragma unroll
  for (int m=1;m<64;m<<=1){ s += __shfl_xor(s,m,64); ss += __shfl_xor(ss,m,64); }
}

__global__ __launch_bounds__(256) void ln_in(const float* __restrict__ x,
    const float* __restrict__ g, const float* __restrict__ be, short* __restrict__ out)
{
  int row=blockIdx.x, tid=threadIdx.x;
  __shared__ float r1[4], r2[4];
  float4 v = ((const float4*)(x + (size_t)row*DM))[tid];
  float s=v.x+v.y+v.z+v.w, ss=v.x*v.x+v.y*v.y+v.z*v.z+v.w*v.w;
  wred2(s,ss);
  if ((tid&63)==0){ r1[tid>>6]=s; r2[tid>>6]=ss; }
  __syncthreads();
  s=r1[0]+r1[1]+r1[2]+r1[3]; ss=r2[0]+r2[1]+r2[2]+r2[3];
  float mu=s*(1.f/DM);
  float rstd=rsqrtf(ss*(1.f/DM)-mu*mu+1e-5f);
  float4 gv=((const float4*)g)[tid], bv=((const float4*)be)[tid];
  s16x4 o;
  o[0]=f2b((v.x-mu)*rstd*gv.x+bv.x);
  o[1]=f2b((v.y-mu)*rstd*gv.y+bv.y);
  o[2]=f2b((v.z-mu)*rstd*gv.z+bv.z);
  o[3]=f2b((v.w-mu)*rstd*gv.w+bv.w);
  *(s16x4*)(out + (size_t)row*DM + tid*4) = o;
}

__global__ __launch_bounds__(256) void ln_chain(const float* __restrict__ x, const float* __restrict__ ao,
    const float* __restrict__ g1, const float* __restrict__ be1,
    const float* __restrict__ g2, const float* __restrict__ be2,
    float* __restrict__ x1, short* __restrict__ h2)
{
  int row=blockIdx.x, tid=threadIdx.x;
  __shared__ float r1[4], r2[4], r3[4], r4[4];
  float4 xv = ((const float4*)(x + (size_t)row*DM))[tid];
  float4 av = ((const float4*)(ao + (size_t)row*DM))[tid];
  float4 y; y.x=xv.x+av.x; y.y=xv.y+av.y; y.z=xv.z+av.z; y.w=xv.w+av.w;
  float s=y.x+y.y+y.z+y.w, ss=y.x*y.x+y.y*y.y+y.z*y.z+y.w*y.w;
  wred2(s,ss);
  if ((tid&63)==0){ r1[tid>>6]=s; r2[tid>>6]=ss; }
  __syncthreads();
  s=r1[0]+r1[1]+r1[2]+r1[3]; ss=r2[0]+r2[1]+r2[2]+r2[3];
  float mu=s*(1.f/DM);
  float rstd=rsqrtf(ss*(1.f/DM)-mu*mu+1e-5f);
  float4 g1v=((const float4*)g1)[tid], b1v=((const float4*)be1)[tid];
  float4 xo;
  xo.x=(y.x-mu)*rstd*g1v.x+b1v.x;
  xo.y=(y.y-mu)*rstd*g1v.y+b1v.y;
  xo.z=(y.z-mu)*rstd*g1v.z+b1v.z;
  xo.w=(y.w-mu)*rstd*g1v.w+b1v.w;
  ((float4*)(x1 + (size_t)row*DM))[tid] = xo;
  float s2=xo.x+xo.y+xo.z+xo.w, ss2=xo.x*xo.x+xo.y*xo.y+xo.z*xo.z+xo.w*xo.w;
  wred2(s2,ss2);
  if ((tid&63)==0){ r3[tid>>6]=s2; r4[tid>>6]=ss2; }
  __syncthreads();
  s2=r3[0]+r3[1]+r3[2]+r3[3]; ss2=r4[0]+r4[1]+r4[2]+r4[3];
  float mu2=s2*(1.f/DM);
  float rstd2=rsqrtf(ss2*(1.f/DM)-mu2*mu2+1e-5f);
  float4 g2v=((const float4*)g2)[tid], b2v=((const float4*)be2)[tid];
  s16x4 o;
  o[0]=f2b((xo.x-mu2)*rstd2*g2v.x+b2v.x);
  o[1]=f2b((xo.y-mu2)*rstd2*g2v.y+b2v.y);
  o[2]=f2b((xo.z-mu2)*rstd2*g2v.z+b2v.z);
  o[3]=f2b((xo.w-mu2)*rstd2*g2v.w+b2v.w);
  *(s16x4*)(h2 + (size_t)row*DM + tid*4) = o;
}

__global__ __launch_bounds__(256) void ln_out_k(const float* __restrict__ a, const float* __restrict__ bsrc,
    const float* __restrict__ g, const float* __restrict__ be, float* __restrict__ out)
{
  int row=blockIdx.x, tid=threadIdx.x;
  __shared__ float r1[4], r2[4];
  float4 xv = ((const float4*)(a + (size_t)row*DM))[tid];
  float4 av = ((const float4*)(bsrc + (size_t)row*DM))[tid];
  float4 y; y.x=xv.x+av.x; y.y=xv.y+av.y; y.z=xv.z+av.z; y.w=xv.w+av.w;
  float s=y.x+y.y+y.z+y.w, ss=y.x*y.x+y.y*y.y+y.z*y.z+y.w*y.w;
  wred2(s,ss);
  if ((tid&63)==0){ r1[tid>>6]=s; r2[tid>>6]=ss; }
  __syncthreads();
  s=r1[0]+r1[1]+r1[2]+r1[3]; ss=r2[0]+r2[1]+r2[2]+r2[3];
  float mu=s*(1.f/DM);
  float rstd=rsqrtf(ss*(1.f/DM)-mu*mu+1e-5f);
  float4 gv=((const float4*)g)[tid], bv=((const float4*)be)[tid];
  float4 o;
  o.x=(y.x-mu)*rstd*gv.x+bv.x;
  o.y=(y.y-mu)*rstd*gv.y+bv.y;
  o.z=(y.z-mu)*rstd*gv.z+bv.z;
  o.w=(y.w-mu)*rstd*gv.w+bv.w;
  ((float4*)(out + (size_t)row*DM))[tid] = o;
}

// ---------------- cast + transpose: w[R][C] f32 -> wt[C][R] bf16 ----------------
__global__ __launch_bounds__(256) void cast_t(const float* __restrict__ w, short* __restrict__ wt, int R, int C)
{
  __shared__ short t[64][65];
  int nbr = R>>6;
  int br = (int)blockIdx.x % nbr, bc = (int)blockIdx.x / nbr;
  int tid = threadIdx.x;
  #pragma unroll
  for (int i=0;i<4;i++){
    int c = i*256 + tid;
    int r = c>>4, c4 = (c&15)*4;
    float4 v = *(const float4*)(w + (size_t)(br*64 + r)*C + bc*64 + c4);
    t[r][c4+0]=f2b(v.x); t[r][c4+1]=f2b(v.y); t[r][c4+2]=f2b(v.z); t[r][c4+3]=f2b(v.w);
  }
  __syncthreads();
  #pragma unroll
  for (int i=0;i<4;i++){
    int c = i*256 + tid;
    int oc = c>>4, c4 = (c&15)*4;
    s16x4 p;
    p[0]=t[c4+0][oc]; p[1]=t[c4+1][oc]; p[2]=t[c4+2][oc]; p[3]=t[c4+3][oc];
    *(s16x4*)&wt[(size_t)(bc*64 + oc)*R + br*64 + c4] = p;
  }
}

// ---------------- launcher ----------------
extern "C" void kernel_launch(void* const* d_in, const int* in_sizes, int n_in,
                              void* d_out, int out_size, void* d_ws, size_t ws_size,
                              hipStream_t stream)
{
  const float* x      = (const float*)d_in[0];
  const float* qkv_w  = (const float*)d_in[1];
  const float* qkv_b  = (const float*)d_in[2];
  const float* out_w  = (const float*)d_in[3];
  const float* out_b  = (const float*)d_in[4];
  const float* aln_g  = (const float*)d_in[5];
  const float* aln_b  = (const float*)d_in[6];
  const float* n1_g   = (const float*)d_in[7];
  const float* n1_b   = (const float*)d_in[8];
  const float* fln_g  = (const float*)d_in[9];
  const float* fln_b  = (const float*)d_in[10];
  const float* w1     = (const float*)d_in[11];
  const float* b1     = (const float*)d_in[12];
  const float* w2     = (const float*)d_in[13];
  const float* b2     = (const float*)d_in[14];
  const float* n2_g   = (const float*)d_in[15];
  const float* n2_b   = (const float*)d_in[16];

  char* ws = (char*)d_ws;
  short* wqkvT = (short*)(ws + 0);          // [3072][1024] bf16
  short* woutT = (short*)(ws + 6291456);    // [1024][1024]
  short* w1T   = (short*)(ws + 8388608);    // [4096][1024]
  short* w2T   = (short*)(ws + 16777216);   // [1024][4096]
  short* h1    = (short*)(ws + 25165824);   // [4096][1024] bf16 (reused as h2)
  short* qkv   = (short*)(ws + 33554432);   // [4096][3072] bf16
  float* attn_out = (float*)(ws + 33554432);// aliases qkv (dead by then)
  short* ff1   = (short*)(ws + 33554432);   // [4096][4096] bf16, aliases qkv+ctx
  short* ctx   = (short*)(ws + 58720256);   // [4096][1024] bf16
  float* x1    = (float*)(ws + 67108864);   // [4096][1024] f32
  float* ff2   = (float*)(ws + 83886080);   // [4096][1024] f32
  float* outp  = (float*)d_out;

  cast_t<<<dim3(16*48),256,0,stream>>>(qkv_w, wqkvT, 1024, 3072);
  cast_t<<<dim3(16*16),256,0,stream>>>(out_w, woutT, 1024, 1024);
  cast_t<<<dim3(16*64),256,0,stream>>>(w1,    w1T,   1024, 4096);
  cast_t<<<dim3(64*16),256,0,stream>>>(w2,    w2T,   4096, 1024);

  ln_in<<<NTOK,256,0,stream>>>(x, aln_g, aln_b, h1);
  gemm8p<0><<<dim3(16*12),512,0,stream>>>(h1, wqkvT, qkv_b, qkv, 4096,3072,1024);
  attn_fwd<<<dim3(32,32),256,0,stream>>>(qkv, ctx);
  gemm_bt<0,0><<<dim3(32*8),256,0,stream>>>(ctx, woutT, out_b, attn_out, 4096,1024,1024);
  ln_chain<<<NTOK,256,0,stream>>>(x, attn_out, n1_g, n1_b, fln_g, fln_b, x1, h1);
  gemm8p<1><<<dim3(16*16),512,0,stream>>>(h1, w1T, b1, ff1, 4096,4096,1024);
  gemm_bt<0,0><<<dim3(32*8),256,0,stream>>>(ff1, w2T, b2, ff2, 4096,1024,4096);
  ln_out_k<<<NTOK,256,0,stream>>>(x1, ff2, n2_g, n2_b, outp);
}

// Round 5
// 310.147 us; speedup vs baseline: 1.3113x; 1.0956x over previous
//
#include <hip/hip_runtime.h>
#include <hip/hip_bf16.h>

typedef __attribute__((ext_vector_type(4))) float f32x4;
typedef __attribute__((ext_vector_type(16))) float f32x16;
typedef __attribute__((ext_vector_type(8))) short s16x8;
typedef __attribute__((ext_vector_type(4))) short s16x4;

#define DM 1024
#define NH 16
#define NB 2
#define NS 2048
#define NTOK (NB*NS)

__device__ __forceinline__ float b2f(short u){
  union { unsigned int i; float f; } c; c.i = ((unsigned int)(unsigned short)u) << 16; return c.f;
}
__device__ __forceinline__ short f2b(float f){
  __hip_bfloat16 h = __float2bfloat16(f);
  return __builtin_bit_cast(short, h);
}
__device__ __forceinline__ void gload16(const void* g, void* l){
  __builtin_amdgcn_global_load_lds((const __attribute__((address_space(1))) void*)g,
                                   (__attribute__((address_space(3))) void*)l, 16, 0, 0);
}
__device__ __forceinline__ s16x4 tr16(const void* p){
  s16x4 r;
  asm volatile("ds_read_b64_tr_b16 %0, %1"
               : "=v"(r)
               : "v"((const __attribute__((address_space(3))) short*)p)
               : "memory");
  return r;
}

#define BARX { __builtin_amdgcn_sched_barrier(0); __builtin_amdgcn_s_barrier(); __builtin_amdgcn_sched_barrier(0); }
#define LGK  { asm volatile("s_waitcnt lgkmcnt(0)" ::: "memory"); __builtin_amdgcn_sched_barrier(0); }

// ======== 256x256 8-phase GEMM (T1+T2+T3+T4+T5), BK=64, 2 K-tiles/iter ========
template<int MIH>
__device__ __forceinline__ void rdA(s16x8 (&Af)[4][2], const short* Ab, int foff){
  #pragma unroll
  for (int m=0;m<4;m++)
    #pragma unroll
    for (int ks=0;ks<2;ks++)
      Af[m][ks] = *(const s16x8*)(Ab + (MIH*4+m)*1024 + ks*512 + foff);
}
template<int NIH>
__device__ __forceinline__ void rdB(s16x8 (&Bf)[4][2], const short* Bb, int foff){
  #pragma unroll
  for (int n=0;n<2;n++)
    #pragma unroll
    for (int ks=0;ks<2;ks++)
      Bf[NIH*2+n][ks] = *(const s16x8*)(Bb + (NIH*2+n)*1024 + ks*512 + foff);
}
template<int MIH,int NIH>
__device__ __forceinline__ void mmQ(f32x4 (&acc)[8][4], s16x8 (&Af)[4][2], s16x8 (&Bf)[4][2]){
  __builtin_amdgcn_s_setprio(1);
  #pragma unroll
  for (int m=0;m<4;m++)
    #pragma unroll
    for (int n=0;n<2;n++)
      #pragma unroll
      for (int ks=0;ks<2;ks++)
        acc[MIH*4+m][NIH*2+n] = __builtin_amdgcn_mfma_f32_16x16x32_bf16(
            Af[m][ks], Bf[NIH*2+n][ks], acc[MIH*4+m][NIH*2+n], 0,0,0);
  __builtin_amdgcn_s_setprio(0);
}

template<int GELU>
__global__ __launch_bounds__(512,2) void gemm8p(
    const short* __restrict__ A, const short* __restrict__ Bt,
    const float* __restrict__ bias, short* __restrict__ C,
    int M, int N, int K)
{
  __shared__ short Al[2*16384];
  __shared__ short Bl[2*16384];
  int tid = threadIdx.x, wid = tid>>6, lane = tid&63;
  int la = lane&15, lb = lane>>4;
  int nbn = N>>8;
  int nwg = (M>>8)*nbn;
  int bid = (int)blockIdx.x;
  int sid = (bid&7)*(nwg>>3) + (bid>>3);
  int bm = sid / nbn, bn = sid % nbn;
  int wm2 = wid>>2, wn4 = wid&3;
  int bhalf = wn4>>1, bq4 = (wn4&1)*4;

  const short* aA0 = A  + (size_t)(bm*256)*K;
  const short* aA1 = A  + (size_t)(bm*256+128)*K;
  const short* bB0 = Bt + (size_t)(bn*256)*K;
  const short* bB1 = Bt + (size_t)(bn*256+128)*K;

  auto stG = [&](short* dstHalf, const short* srcRow0, int kt){
    #pragma unroll
    for (int c=0;c<2;c++){
      int s = c*8 + wid;
      int row = ((s>>1)<<4) + (lane>>2);
      int kk  = kt + ((s&1)<<5) + (((lane&3)<<3) ^ ((lane&32)>>1));
      gload16(srcRow0 + (size_t)row*K + kk, dstHalf + s*512);
    }
  };

  int NJ = K>>7;
  stG(&Al[0], aA0, 0);      stG(&Al[8192], aA1, 0);
  stG(&Bl[0], bB0, 0);      stG(&Bl[8192], bB1, 0);
  stG(&Bl[16384], bB0, 64); stG(&Bl[16384+8192], bB1, 64);
  asm volatile("s_waitcnt vmcnt(4)" ::: "memory");
  BARX;

  f32x4 acc[8][4] = {};
  s16x8 Af[4][2], Bf[4][2];
  int foff = la*32 + ((lb*8) ^ ((la&8)<<1));

  const short* Ab0c = &Al[wm2*8192];
  const short* Ab1c = &Al[16384 + wm2*8192];
  const short* Bb0c = &Bl[bhalf*8192 + bq4*1024];
  const short* Bb1c = &Bl[16384 + bhalf*8192 + bq4*1024];

  for (int j=0;j<NJ;j++){
    bool more = (j+1 < NJ);
    int ktA  = (2*j+1)*64;
    int ktN0 = (2*j+2)*64, ktN1 = (2*j+3)*64;
    rdA<0>(Af, Ab0c, foff); rdB<0>(Bf, Bb0c, foff);
    stG(&Al[16384], aA0, ktA);
    BARX; LGK; mmQ<0,0>(acc,Af,Bf); BARX;
    rdB<1>(Bf, Bb0c, foff);
    stG(&Al[16384+8192], aA1, ktA);
    BARX; LGK; mmQ<0,1>(acc,Af,Bf); BARX;
    rdA<1>(Af, Ab0c, foff);
    if (more) stG(&Bl[0], bB0, ktN0);
    BARX; LGK; mmQ<1,1>(acc,Af,Bf); BARX;
    if (more){ stG(&Bl[8192], bB1, ktN0);
               asm volatile("s_waitcnt vmcnt(4)" ::: "memory"); }
    else     { asm volatile("s_waitcnt vmcnt(0)" ::: "memory"); }
    BARX; mmQ<1,0>(acc,Af,Bf); BARX;
    rdA<0>(Af, Ab1c, foff); rdB<0>(Bf, Bb1c, foff);
    if (more) stG(&Al[0], aA0, ktN0);
    BARX; LGK; mmQ<0,0>(acc,Af,Bf); BARX;
    rdB<1>(Bf, Bb1c, foff);
    if (more) stG(&Al[8192], aA1, ktN0);
    BARX; LGK; mmQ<0,1>(acc,Af,Bf); BARX;
    rdA<1>(Af, Ab1c, foff);
    if (more) stG(&Bl[16384], bB0, ktN1);
    BARX; LGK; mmQ<1,1>(acc,Af,Bf); BARX;
    if (more){ stG(&Bl[16384+8192], bB1, ktN1);
               asm volatile("s_waitcnt vmcnt(4)" ::: "memory"); }
    else     { asm volatile("s_waitcnt vmcnt(0)" ::: "memory"); }
    BARX; mmQ<1,0>(acc,Af,Bf); BARX;
  }

  #pragma unroll
  for (int ni=0;ni<4;ni++){
    int col = bn*256 + wn4*64 + ni*16 + la;
    float bv = bias[col];
    #pragma unroll
    for (int mi=0;mi<8;mi++){
      int row0 = bm*256 + wm2*128 + mi*16 + lb*4;
      #pragma unroll
      for (int j=0;j<4;j++){
        float v = acc[mi][ni][j] + bv;
        if (GELU) v = 0.5f*v*(1.0f + erff(v*0.70710678118f));
        C[(size_t)(row0+j)*N + col] = f2b(v);
      }
    }
  }
}

// ---------------- GEMM: C[M,N] = A[M,K](bf16) * Bt[N,K](bf16)^T + bias ----------------
template<int GELU, int OUTBF16>
__global__ __launch_bounds__(256,2) void gemm_bt(
    const short* __restrict__ A, const short* __restrict__ Bt,
    const float* __restrict__ bias, void* __restrict__ Cv,
    int M, int N, int K)
{
  __shared__ short Al[128*64];
  __shared__ short Bl[128*64];
  int tid = threadIdx.x, wid = tid>>6, lane = tid&63;
  int la = lane&15, lb = lane>>4;
  int nbn = N>>7;
  int nwg = (M>>7)*nbn;
  int bid = (int)blockIdx.x;
  int sid = ((nwg&7)==0) ? ((bid&7)*(nwg>>3) + (bid>>3)) : bid;
  int bm = sid / nbn, bn = sid % nbn;
  int wm = (wid>>1)<<6, wn = (wid&1)<<6;
  f32x4 acc[4][4] = {};
  for (int kt=0; kt<K; kt+=64){
    #pragma unroll
    for (int i=0;i<4;i++){
      int c = i*256+tid; int r=c>>3, col=(c&7)<<3;
      gload16(A + (size_t)(bm*128+r)*K + kt + col, &Al[(i*256+wid*64)*8]);
    }
    #pragma unroll
    for (int i=0;i<4;i++){
      int c = i*256+tid; int r=c>>3, col=(c&7)<<3;
      gload16(Bt + (size_t)(bn*128+r)*K + kt + col, &Bl[(i*256+wid*64)*8]);
    }
    __syncthreads();
    #pragma unroll
    for (int ks=0;ks<64;ks+=32){
      s16x8 af[4], bfr[4];
      #pragma unroll
      for (int mi=0;mi<4;mi++) af[mi]  = *(const s16x8*)&Al[(wm+mi*16+la)*64 + ks + lb*8];
      #pragma unroll
      for (int ni=0;ni<4;ni++) bfr[ni] = *(const s16x8*)&Bl[(wn+ni*16+la)*64 + ks + lb*8];
      #pragma unroll
      for (int mi=0;mi<4;mi++)
        #pragma unroll
        for (int ni=0;ni<4;ni++)
          acc[mi][ni] = __builtin_amdgcn_mfma_f32_16x16x32_bf16(af[mi], bfr[ni], acc[mi][ni], 0,0,0);
    }
    __syncthreads();
  }
  #pragma unroll
  for (int ni=0;ni<4;ni++){
    int col = bn*128 + wn + ni*16 + la;
    float bv = bias[col];
    #pragma unroll
    for (int mi=0;mi<4;mi++){
      int row0 = bm*128 + wm + mi*16 + lb*4;
      #pragma unroll
      for (int j=0;j<4;j++){
        float v = acc[mi][ni][j] + bv;
        if (GELU) v = 0.5f*v*(1.0f + erff(v*0.70710678118f));
        if (OUTBF16) ((short*)Cv)[(size_t)(row0+j)*N + col] = f2b(v);
        else ((float*)Cv)[(size_t)(row0+j)*N + col] = v;
      }
    }
  }
}

// ---------------- Flash attention, 8-warp 32x32 swapped-QK structure ----------------
// Per block: 512 threads = 8 warps x 32 q-rows = 256 q-rows; KV tiles of 64, double-buffered.
// K LDS: [64][64] bf16 rows swizzled byte^=((row&7)<<4); staged linearly w/ pre-swizzled source.
// V LDS: tr16-subtiled: byte = dh*4096 + ks*1024 + hi*512 + lb0*128 + jj*32 + la*2
//        holding V[16ks+8hi+4jh... (jh via +256)][32dh+16lb0+la].
// QK swapped: sacc = mfma(K,Q) -> lane holds P^T[k][q=lane&31]; softmax lane-local + 1 shfl.
// PV A-frag built in-register: bf16x2 packs + shfl_xor(32) partner exchange + selects.
__global__ __launch_bounds__(512,1) void attn_fwd(const short* __restrict__ qkv, short* __restrict__ ctx)
{
  __shared__ short KlS[2*4096];
  __shared__ short VlS[2*4096];
  __shared__ float stats[8*32];
  char* Kl = (char*)KlS; char* Vl = (char*)VlS;
  int tid=threadIdx.x, w=tid>>6, lane=tid&63;
  int q5=lane&31, hi=lane>>5, la=lane&15, lb0=(lane>>4)&1;
  int qt=blockIdx.x, bh=blockIdx.y;
  int b=bh>>4, h=bh&15;
  int q0w = qt*256 + w*32;

  // Q fragments (B-operand): qf[ds] = Q[q0w+q5][ds*16 + hi*8 + 0..7], pre-scaled
  const short* qp = qkv + (size_t)(b*NS+q0w+q5)*3072 + h*64 + hi*8;
  s16x8 qf[4];
  #pragma unroll
  for (int ds=0; ds<4; ds++){
    s16x8 v = *(const s16x8*)(qp + ds*16);
    #pragma unroll
    for (int j=0;j<8;j++) v[j] = f2b(b2f(v[j])*0.125f);
    qf[ds]=v;
  }

  // staging sources (per tile add t*64*3072)
  int krow = 8*w + (lane>>3);
  int kcolS = (((lane&7) ^ ((lane>>3)&7)) << 3);
  const short* Ksrc = qkv + (size_t)(b*NS+krow)*3072 + h*64 + 1024 + kcolS;
  int vk = 16*(w&3) + 8*hi + 4*lb0 + ((lane>>1)&3);
  int vd = 32*(w>>2) + 16*((lane>>3)&1) + 8*(lane&1);
  const short* Vsrc = qkv + (size_t)(b*NS+vk)*3072 + h*64 + 2048 + vd;

  // fragment read bases
  int sw = (q5&7)<<4;
  int baseK = q5*128 + ((hi<<4) ^ (sw&16)) + (sw&96);
  int baseV = hi*512 + lb0*128 + la*8;

  f32x16 cacc0={}, cacc1={};
  float mrow=-1e30f, lrow=0.f;
  const size_t tstep = (size_t)64*3072;

  gload16(Ksrc, Kl + w*1024);
  gload16(Vsrc, Vl + w*1024);
  __syncthreads();
  int cur=0;

  for (int t=0;t<NS/64;t++){
    if (t+1 < NS/64){
      gload16(Ksrc + (size_t)(t+1)*tstep, Kl + (cur^1)*8192 + w*1024);
      gload16(Vsrc + (size_t)(t+1)*tstep, Vl + (cur^1)*8192 + w*1024);
    }
    // ---- QK^T (swapped): s{0,1} = K[32s+..] . Q ----
    const char* Kb = Kl + cur*8192;
    f32x16 s0={}, s1={};
    #pragma unroll
    for (int ds=0; ds<4; ds++){
      s16x8 k0 = *(const s16x8*)(Kb + (baseK ^ (ds<<5)));
      s16x8 k1 = *(const s16x8*)(Kb + 4096 + (baseK ^ (ds<<5)));
      s0 = __builtin_amdgcn_mfma_f32_32x32x16_bf16(k0, qf[ds], s0, 0,0,0);
      s1 = __builtin_amdgcn_mfma_f32_32x32x16_bf16(k1, qf[ds], s1, 0,0,0);
    }
    // ---- online softmax (defer-max THR=8) ----
    float pmax = s0[0];
    #pragma unroll
    for (int r=1;r<16;r++) pmax = fmaxf(pmax, s0[r]);
    #pragma unroll
    for (int r=0;r<16;r++) pmax = fmaxf(pmax, s1[r]);
    pmax = fmaxf(pmax, __shfl_xor(pmax, 32, 64));
    if (__any(pmax > mrow + 8.f)){
      float mnew = fmaxf(mrow, pmax);
      float corr = __expf(mrow - mnew);
      if (!hi) stats[w*32+q5] = corr;
      LGK;
      lrow *= corr; mrow = mnew;
      #pragma unroll
      for (int r=0;r<16;r++){
        float c = stats[w*32 + ((r&3)+8*(r>>2)+4*hi)];
        cacc0[r]*=c; cacc1[r]*=c;
      }
    }
    float rs = 0.f;
    #pragma unroll
    for (int r=0;r<16;r++){ float p=__expf(s0[r]-mrow); s0[r]=p; rs+=p; }
    #pragma unroll
    for (int r=0;r<16;r++){ float p=__expf(s1[r]-mrow); s1[r]=p; rs+=p; }
    rs += __shfl_xor(rs, 32, 64);
    lrow += rs;
    // ---- pack P and build PV A-fragments ----
    unsigned int D0[4][2], D1[4][2], R0[4][2], R1[4][2];
    #pragma unroll
    for (int bb=0;bb<4;bb++)
      #pragma unroll
      for (int hh=0;hh<2;hh++){
        D0[bb][hh] = (unsigned int)(unsigned short)f2b(s0[4*bb+2*hh]) |
                     ((unsigned int)(unsigned short)f2b(s0[4*bb+2*hh+1])<<16);
        D1[bb][hh] = (unsigned int)(unsigned short)f2b(s1[4*bb+2*hh]) |
                     ((unsigned int)(unsigned short)f2b(s1[4*bb+2*hh+1])<<16);
      }
    #pragma unroll
    for (int bb=0;bb<4;bb++)
      #pragma unroll
      for (int hh=0;hh<2;hh++){
        R0[bb][hh] = (unsigned int)__shfl_xor((int)D0[bb][hh], 32, 64);
        R1[bb][hh] = (unsigned int)__shfl_xor((int)D1[bb][hh], 32, 64);
      }
    union PA { unsigned int u[4]; s16x8 v; } pa[4];
    #pragma unroll
    for (int e=0;e<2;e++)
      #pragma unroll
      for (int hh=0;hh<2;hh++){
        pa[e].u[hh]     = hi ? R0[2*e+1][hh] : D0[2*e][hh];
        pa[e].u[2+hh]   = hi ? D0[2*e+1][hh] : R0[2*e][hh];
        pa[2+e].u[hh]   = hi ? R1[2*e+1][hh] : D1[2*e][hh];
        pa[2+e].u[2+hh] = hi ? D1[2*e+1][hh] : R1[2*e][hh];
      }
    // ---- PV ----
    const char* Vb = Vl + cur*8192;
    #pragma unroll
    for (int ks=0;ks<4;ks++){
      s16x4 t00 = tr16(Vb + ks*1024 +        0 + baseV);
      s16x4 t01 = tr16(Vb + ks*1024 +      256 + baseV);
      s16x4 t10 = tr16(Vb + ks*1024 + 4096     + baseV);
      s16x4 t11 = tr16(Vb + ks*1024 + 4096+256 + baseV);
      LGK;
      union { s16x4 hh[2]; s16x8 v; } u0, u1;
      u0.hh[0]=t00; u0.hh[1]=t01;
      u1.hh[0]=t10; u1.hh[1]=t11;
      cacc0 = __builtin_amdgcn_mfma_f32_32x32x16_bf16(pa[ks].v, u0.v, cacc0, 0,0,0);
      cacc1 = __builtin_amdgcn_mfma_f32_32x32x16_bf16(pa[ks].v, u1.v, cacc1, 0,0,0);
    }
    __syncthreads();
    cur ^= 1;
  }
  // ---- epilogue ----
  if (!hi) stats[w*32+q5] = 1.0f/lrow;
  LGK;
  #pragma unroll
  for (int r=0;r<16;r++){
    int q = (r&3)+8*(r>>2)+4*hi;
    float linv = stats[w*32+q];
    size_t row = (size_t)(b*NS + q0w + q)*DM + h*64;
    ctx[row + q5]      = f2b(cacc0[r]*linv);
    ctx[row + 32 + q5] = f2b(cacc1[r]*linv);
  }
}

// ---------------- LayerNorm kernels ----------------
__device__ __forceinline__ void wred2(float& s, float& ss){
  #pragma unroll
  for (int m=1;m<64;m<<=1){ s += __shfl_xor(s,m,64); ss += __shfl_xor(ss,m,64); }
}

__global__ __launch_bounds__(256) void ln_in(const float* __restrict__ x,
    const float* __restrict__ g, const float* __restrict__ be, short* __restrict__ out)
{
  int row=blockIdx.x, tid=threadIdx.x;
  __shared__ float r1[4], r2[4];
  float4 v = ((const float4*)(x + (size_t)row*DM))[tid];
  float s=v.x+v.y+v.z+v.w, ss=v.x*v.x+v.y*v.y+v.z*v.z+v.w*v.w;
  wred2(s,ss);
  if ((tid&63)==0){ r1[tid>>6]=s; r2[tid>>6]=ss; }
  __syncthreads();
  s=r1[0]+r1[1]+r1[2]+r1[3]; ss=r2[0]+r2[1]+r2[2]+r2[3];
  float mu=s*(1.f/DM);
  float rstd=rsqrtf(ss*(1.f/DM)-mu*mu+1e-5f);
  float4 gv=((const float4*)g)[tid], bv=((const float4*)be)[tid];
  s16x4 o;
  o[0]=f2b((v.x-mu)*rstd*gv.x+bv.x);
  o[1]=f2b((v.y-mu)*rstd*gv.y+bv.y);
  o[2]=f2b((v.z-mu)*rstd*gv.z+bv.z);
  o[3]=f2b((v.w-mu)*rstd*gv.w+bv.w);
  *(s16x4*)(out + (size_t)row*DM + tid*4) = o;
}

__global__ __launch_bounds__(256) void ln_chain(const float* __restrict__ x, const float* __restrict__ ao,
    const float* __restrict__ g1, const float* __restrict__ be1,
    const float* __restrict__ g2, const float* __restrict__ be2,
    float* __restrict__ x1, short* __restrict__ h2)
{
  int row=blockIdx.x, tid=threadIdx.x;
  __shared__ float r1[4], r2[4], r3[4], r4[4];
  float4 xv = ((const float4*)(x + (size_t)row*DM))[tid];
  float4 av = ((const float4*)(ao + (size_t)row*DM))[tid];
  float4 y; y.x=xv.x+av.x; y.y=xv.y+av.y; y.z=xv.z+av.z; y.w=xv.w+av.w;
  float s=y.x+y.y+y.z+y.w, ss=y.x*y.x+y.y*y.y+y.z*y.z+y.w*y.w;
  wred2(s,ss);
  if ((tid&63)==0){ r1[tid>>6]=s; r2[tid>>6]=ss; }
  __syncthreads();
  s=r1[0]+r1[1]+r1[2]+r1[3]; ss=r2[0]+r2[1]+r2[2]+r2[3];
  float mu=s*(1.f/DM);
  float rstd=rsqrtf(ss*(1.f/DM)-mu*mu+1e-5f);
  float4 g1v=((const float4*)g1)[tid], b1v=((const float4*)be1)[tid];
  float4 xo;
  xo.x=(y.x-mu)*rstd*g1v.x+b1v.x;
  xo.y=(y.y-mu)*rstd*g1v.y+b1v.y;
  xo.z=(y.z-mu)*rstd*g1v.z+b1v.z;
  xo.w=(y.w-mu)*rstd*g1v.w+b1v.w;
  ((float4*)(x1 + (size_t)row*DM))[tid] = xo;
  float s2=xo.x+xo.y+xo.z+xo.w, ss2=xo.x*xo.x+xo.y*xo.y+xo.z*xo.z+xo.w*xo.w;
  wred2(s2,ss2);
  if ((tid&63)==0){ r3[tid>>6]=s2; r4[tid>>6]=ss2; }
  __syncthreads();
  s2=r3[0]+r3[1]+r3[2]+r3[3]; ss2=r4[0]+r4[1]+r4[2]+r4[3];
  float mu2=s2*(1.f/DM);
  float rstd2=rsqrtf(ss2*(1.f/DM)-mu2*mu2+1e-5f);
  float4 g2v=((const float4*)g2)[tid], b2v=((const float4*)be2)[tid];
  s16x4 o;
  o[0]=f2b((xo.x-mu2)*rstd2*g2v.x+b2v.x);
  o[1]=f2b((xo.y-mu2)*rstd2*g2v.y+b2v.y);
  o[2]=f2b((xo.z-mu2)*rstd2*g2v.z+b2v.z);
  o[3]=f2b((xo.w-mu2)*rstd2*g2v.w+b2v.w);
  *(s16x4*)(h2 + (size_t)row*DM + tid*4) = o;
}

__global__ __launch_bounds__(256) void ln_out_k(const float* __restrict__ a, const float* __restrict__ bsrc,
    const float* __restrict__ g, const float* __restrict__ be, float* __restrict__ out)
{
  int row=blockIdx.x, tid=threadIdx.x;
  __shared__ float r1[4], r2[4];
  float4 xv = ((const float4*)(a + (size_t)row*DM))[tid];
  float4 av = ((const float4*)(bsrc + (size_t)row*DM))[tid];
  float4 y; y.x=xv.x+av.x; y.y=xv.y+av.y; y.z=xv.z+av.z; y.w=xv.w+av.w;
  float s=y.x+y.y+y.z+y.w, ss=y.x*y.x+y.y*y.y+y.z*y.z+y.w*y.w;
  wred2(s,ss);
  if ((tid&63)==0){ r1[tid>>6]=s; r2[tid>>6]=ss; }
  __syncthreads();
  s=r1[0]+r1[1]+r1[2]+r1[3]; ss=r2[0]+r2[1]+r2[2]+r2[3];
  float mu=s*(1.f/DM);
  float rstd=rsqrtf(ss*(1.f/DM)-mu*mu+1e-5f);
  float4 gv=((const float4*)g)[tid], bv=((const float4*)be)[tid];
  float4 o;
  o.x=(y.x-mu)*rstd*gv.x+bv.x;
  o.y=(y.y-mu)*rstd*gv.y+bv.y;
  o.z=(y.z-mu)*rstd*gv.z+bv.z;
  o.w=(y.w-mu)*rstd*gv.w+bv.w;
  ((float4*)(out + (size_t)row*DM))[tid] = o;
}

// ---------------- cast + transpose: w[R][C] f32 -> wt[C][R] bf16 ----------------
__global__ __launch_bounds__(256) void cast_t(const float* __restrict__ w, short* __restrict__ wt, int R, int C)
{
  __shared__ short t[64][65];
  int nbr = R>>6;
  int br = (int)blockIdx.x % nbr, bc = (int)blockIdx.x / nbr;
  int tid = threadIdx.x;
  #pragma unroll
  for (int i=0;i<4;i++){
    int c = i*256 + tid;
    int r = c>>4, c4 = (c&15)*4;
    float4 v = *(const float4*)(w + (size_t)(br*64 + r)*C + bc*64 + c4);
    t[r][c4+0]=f2b(v.x); t[r][c4+1]=f2b(v.y); t[r][c4+2]=f2b(v.z); t[r][c4+3]=f2b(v.w);
  }
  __syncthreads();
  #pragma unroll
  for (int i=0;i<4;i++){
    int c = i*256 + tid;
    int oc = c>>4, c4 = (c&15)*4;
    s16x4 p;
    p[0]=t[c4+0][oc]; p[1]=t[c4+1][oc]; p[2]=t[c4+2][oc]; p[3]=t[c4+3][oc];
    *(s16x4*)&wt[(size_t)(bc*64 + oc)*R + br*64 + c4] = p;
  }
}

// ---------------- launcher ----------------
extern "C" void kernel_launch(void* const* d_in, const int* in_sizes, int n_in,
                              void* d_out, int out_size, void* d_ws, size_t ws_size,
                              hipStream_t stream)
{
  const float* x      = (const float*)d_in[0];
  const float* qkv_w  = (const float*)d_in[1];
  const float* qkv_b  = (const float*)d_in[2];
  const float* out_w  = (const float*)d_in[3];
  const float* out_b  = (const float*)d_in[4];
  const float* aln_g  = (const float*)d_in[5];
  const float* aln_b  = (const float*)d_in[6];
  const float* n1_g   = (const float*)d_in[7];
  const float* n1_b   = (const float*)d_in[8];
  const float* fln_g  = (const float*)d_in[9];
  const float* fln_b  = (const float*)d_in[10];
  const float* w1     = (const float*)d_in[11];
  const float* b1     = (const float*)d_in[12];
  const float* w2     = (const float*)d_in[13];
  const float* b2     = (const float*)d_in[14];
  const float* n2_g   = (const float*)d_in[15];
  const float* n2_b   = (const float*)d_in[16];

  char* ws = (char*)d_ws;
  short* wqkvT = (short*)(ws + 0);          // [3072][1024] bf16
  short* woutT = (short*)(ws + 6291456);    // [1024][1024]
  short* w1T   = (short*)(ws + 8388608);    // [4096][1024]
  short* w2T   = (short*)(ws + 16777216);   // [1024][4096]
  short* h1    = (short*)(ws + 25165824);   // [4096][1024] bf16 (reused as h2)
  short* qkv   = (short*)(ws + 33554432);   // [4096][3072] bf16
  float* attn_out = (float*)(ws + 33554432);// aliases qkv (dead by then)
  short* ff1   = (short*)(ws + 33554432);   // [4096][4096] bf16, aliases qkv+ctx
  short* ctx   = (short*)(ws + 58720256);   // [4096][1024] bf16
  float* x1    = (float*)(ws + 67108864);   // [4096][1024] f32
  float* ff2   = (float*)(ws + 83886080);   // [4096][1024] f32
  float* outp  = (float*)d_out;

  cast_t<<<dim3(16*48),256,0,stream>>>(qkv_w, wqkvT, 1024, 3072);
  cast_t<<<dim3(16*16),256,0,stream>>>(out_w, woutT, 1024, 1024);
  cast_t<<<dim3(16*64),256,0,stream>>>(w1,    w1T,   1024, 4096);
  cast_t<<<dim3(64*16),256,0,stream>>>(w2,    w2T,   4096, 1024);

  ln_in<<<NTOK,256,0,stream>>>(x, aln_g, aln_b, h1);
  gemm8p<0><<<dim3(16*12),512,0,stream>>>(h1, wqkvT, qkv_b, qkv, 4096,3072,1024);
  attn_fwd<<<dim3(8,32),512,0,stream>>>(qkv, ctx);
  gemm_bt<0,0><<<dim3(32*8),256,0,stream>>>(ctx, woutT, out_b, attn_out, 4096,1024,1024);
  ln_chain<<<NTOK,256,0,stream>>>(x, attn_out, n1_g, n1_b, fln_g, fln_b, x1, h1);
  gemm8p<1><<<dim3(16*16),512,0,stream>>>(h1, w1T, b1, ff1, 4096,4096,1024);
  gemm_bt<0,0><<<dim3(32*8),256,0,stream>>>(ff1, w2T, b2, ff2, 4096,1024,4096);
  ln_out_k<<<NTOK,256,0,stream>>>(x1, ff2, n2_g, n2_b, outp);
}

// Round 6
// 279.204 us; speedup vs baseline: 1.4566x; 1.1108x over previous
//
#include <hip/hip_runtime.h>
#include <hip/hip_bf16.h>

typedef __attribute__((ext_vector_type(4))) float f32x4;
typedef __attribute__((ext_vector_type(16))) float f32x16;
typedef __attribute__((ext_vector_type(8))) short s16x8;
typedef __attribute__((ext_vector_type(4))) short s16x4;

#define DM 1024
#define NH 16
#define NB 2
#define NS 2048
#define NTOK (NB*NS)

__device__ __forceinline__ float b2f(short u){
  union { unsigned int i; float f; } c; c.i = ((unsigned int)(unsigned short)u) << 16; return c.f;
}
__device__ __forceinline__ short f2b(float f){
  __hip_bfloat16 h = __float2bfloat16(f);
  return __builtin_bit_cast(short, h);
}
__device__ __forceinline__ void gload16(const void* g, void* l){
  __builtin_amdgcn_global_load_lds((const __attribute__((address_space(1))) void*)g,
                                   (__attribute__((address_space(3))) void*)l, 16, 0, 0);
}
__device__ __forceinline__ s16x4 tr16(const void* p){
  s16x4 r;
  asm volatile("ds_read_b64_tr_b16 %0, %1"
               : "=v"(r)
               : "v"((const __attribute__((address_space(3))) short*)p)
               : "memory");
  return r;
}

#define BARX { __builtin_amdgcn_sched_barrier(0); __builtin_amdgcn_s_barrier(); __builtin_amdgcn_sched_barrier(0); }
#define LGK  { asm volatile("s_waitcnt lgkmcnt(0)" ::: "memory"); __builtin_amdgcn_sched_barrier(0); }

// ======== 256x256 8-phase GEMM (T1+T2+T3+T4+T5), BK=64, 2 K-tiles/iter ========
// SPLITS>1: blockIdx.z selects K-chunk of Ktot/SPLITS; partial written to Cz (bf16);
// bias only in z==0; GELU only valid with SPLITS==1.
template<int MIH>
__device__ __forceinline__ void rdA(s16x8 (&Af)[4][2], const short* Ab, int foff){
  #pragma unroll
  for (int m=0;m<4;m++)
    #pragma unroll
    for (int ks=0;ks<2;ks++)
      Af[m][ks] = *(const s16x8*)(Ab + (MIH*4+m)*1024 + ks*512 + foff);
}
template<int NIH>
__device__ __forceinline__ void rdB(s16x8 (&Bf)[4][2], const short* Bb, int foff){
  #pragma unroll
  for (int n=0;n<2;n++)
    #pragma unroll
    for (int ks=0;ks<2;ks++)
      Bf[NIH*2+n][ks] = *(const s16x8*)(Bb + (NIH*2+n)*1024 + ks*512 + foff);
}
template<int MIH,int NIH>
__device__ __forceinline__ void mmQ(f32x4 (&acc)[8][4], s16x8 (&Af)[4][2], s16x8 (&Bf)[4][2]){
  __builtin_amdgcn_s_setprio(1);
  #pragma unroll
  for (int m=0;m<4;m++)
    #pragma unroll
    for (int n=0;n<2;n++)
      #pragma unroll
      for (int ks=0;ks<2;ks++)
        acc[MIH*4+m][NIH*2+n] = __builtin_amdgcn_mfma_f32_16x16x32_bf16(
            Af[m][ks], Bf[NIH*2+n][ks], acc[MIH*4+m][NIH*2+n], 0,0,0);
  __builtin_amdgcn_s_setprio(0);
}

template<int GELU, int SPLITS>
__global__ __launch_bounds__(512,2) void gemm8p(
    const short* __restrict__ A, const short* __restrict__ Bt,
    const float* __restrict__ bias,
    short* __restrict__ C0, short* __restrict__ C1,
    short* __restrict__ C2, short* __restrict__ C3,
    int M, int N, int Ktot)
{
  __shared__ short Al[2*16384];
  __shared__ short Bl[2*16384];
  int tid = threadIdx.x, wid = tid>>6, lane = tid&63;
  int la = lane&15, lb = lane>>4;
  int z = blockIdx.z;
  const int Ksp = Ktot / SPLITS;
  short* C = (SPLITS==1) ? C0 : (z==0?C0 : z==1?C1 : z==2?C2 : C3);
  const short* Az  = A  + z*Ksp;
  const short* Btz = Bt + z*Ksp;
  int nbn = N>>8;
  int nwg = (M>>8)*nbn;
  int bid = (int)blockIdx.x;
  int sid = (bid&7)*(nwg>>3) + (bid>>3);
  int bm = sid / nbn, bn = sid % nbn;
  int wm2 = wid>>2, wn4 = wid&3;
  int bhalf = wn4>>1, bq4 = (wn4&1)*4;

  const short* aA0 = Az  + (size_t)(bm*256)*Ktot;
  const short* aA1 = Az  + (size_t)(bm*256+128)*Ktot;
  const short* bB0 = Btz + (size_t)(bn*256)*Ktot;
  const short* bB1 = Btz + (size_t)(bn*256+128)*Ktot;

  auto stG = [&](short* dstHalf, const short* srcRow0, int kt){
    #pragma unroll
    for (int c=0;c<2;c++){
      int s = c*8 + wid;
      int row = ((s>>1)<<4) + (lane>>2);
      int kk  = kt + ((s&1)<<5) + (((lane&3)<<3) ^ ((lane&32)>>1));
      gload16(srcRow0 + (size_t)row*Ktot + kk, dstHalf + s*512);
    }
  };

  int NJ = Ksp>>7;
  stG(&Al[0], aA0, 0);      stG(&Al[8192], aA1, 0);
  stG(&Bl[0], bB0, 0);      stG(&Bl[8192], bB1, 0);
  stG(&Bl[16384], bB0, 64); stG(&Bl[16384+8192], bB1, 64);
  asm volatile("s_waitcnt vmcnt(4)" ::: "memory");
  BARX;

  f32x4 acc[8][4] = {};
  s16x8 Af[4][2], Bf[4][2];
  int foff = la*32 + ((lb*8) ^ ((la&8)<<1));

  const short* Ab0c = &Al[wm2*8192];
  const short* Ab1c = &Al[16384 + wm2*8192];
  const short* Bb0c = &Bl[bhalf*8192 + bq4*1024];
  const short* Bb1c = &Bl[16384 + bhalf*8192 + bq4*1024];

  for (int j=0;j<NJ;j++){
    bool more = (j+1 < NJ);
    int ktA  = (2*j+1)*64;
    int ktN0 = (2*j+2)*64, ktN1 = (2*j+3)*64;
    rdA<0>(Af, Ab0c, foff); rdB<0>(Bf, Bb0c, foff);
    stG(&Al[16384], aA0, ktA);
    BARX; LGK; mmQ<0,0>(acc,Af,Bf); BARX;
    rdB<1>(Bf, Bb0c, foff);
    stG(&Al[16384+8192], aA1, ktA);
    BARX; LGK; mmQ<0,1>(acc,Af,Bf); BARX;
    rdA<1>(Af, Ab0c, foff);
    if (more) stG(&Bl[0], bB0, ktN0);
    BARX; LGK; mmQ<1,1>(acc,Af,Bf); BARX;
    if (more){ stG(&Bl[8192], bB1, ktN0);
               asm volatile("s_waitcnt vmcnt(4)" ::: "memory"); }
    else     { asm volatile("s_waitcnt vmcnt(0)" ::: "memory"); }
    BARX; mmQ<1,0>(acc,Af,Bf); BARX;
    rdA<0>(Af, Ab1c, foff); rdB<0>(Bf, Bb1c, foff);
    if (more) stG(&Al[0], aA0, ktN0);
    BARX; LGK; mmQ<0,0>(acc,Af,Bf); BARX;
    rdB<1>(Bf, Bb1c, foff);
    if (more) stG(&Al[8192], aA1, ktN0);
    BARX; LGK; mmQ<0,1>(acc,Af,Bf); BARX;
    rdA<1>(Af, Ab1c, foff);
    if (more) stG(&Bl[16384], bB0, ktN1);
    BARX; LGK; mmQ<1,1>(acc,Af,Bf); BARX;
    if (more){ stG(&Bl[16384+8192], bB1, ktN1);
               asm volatile("s_waitcnt vmcnt(4)" ::: "memory"); }
    else     { asm volatile("s_waitcnt vmcnt(0)" ::: "memory"); }
    BARX; mmQ<1,0>(acc,Af,Bf); BARX;
  }

  #pragma unroll
  for (int ni=0;ni<4;ni++){
    int col = bn*256 + wn4*64 + ni*16 + la;
    float bv = (SPLITS==1 || z==0) ? bias[col] : 0.0f;
    #pragma unroll
    for (int mi=0;mi<8;mi++){
      int row0 = bm*256 + wm2*128 + mi*16 + lb*4;
      #pragma unroll
      for (int j=0;j<4;j++){
        float v = acc[mi][ni][j] + bv;
        if (GELU) v = 0.5f*v*(1.0f + erff(v*0.70710678118f));
        C[(size_t)(row0+j)*N + col] = f2b(v);
      }
    }
  }
}

// ---------------- Flash attention, 8-warp 32x32 swapped-QK structure ----------------
__global__ __launch_bounds__(512,1) void attn_fwd(const short* __restrict__ qkv, short* __restrict__ ctx)
{
  __shared__ short KlS[2*4096];
  __shared__ short VlS[2*4096];
  __shared__ float stats[8*32];
  char* Kl = (char*)KlS; char* Vl = (char*)VlS;
  int tid=threadIdx.x, w=tid>>6, lane=tid&63;
  int q5=lane&31, hi=lane>>5, la=lane&15, lb0=(lane>>4)&1;
  int qt=blockIdx.x, bh=blockIdx.y;
  int b=bh>>4, h=bh&15;
  int q0w = qt*256 + w*32;

  const short* qp = qkv + (size_t)(b*NS+q0w+q5)*3072 + h*64 + hi*8;
  s16x8 qf[4];
  #pragma unroll
  for (int ds=0; ds<4; ds++){
    s16x8 v = *(const s16x8*)(qp + ds*16);
    #pragma unroll
    for (int j=0;j<8;j++) v[j] = f2b(b2f(v[j])*0.125f);
    qf[ds]=v;
  }

  int krow = 8*w + (lane>>3);
  int kcolS = (((lane&7) ^ ((lane>>3)&7)) << 3);
  const short* Ksrc = qkv + (size_t)(b*NS+krow)*3072 + h*64 + 1024 + kcolS;
  int vk = 16*(w&3) + 8*hi + 4*lb0 + ((lane>>1)&3);
  int vd = 32*(w>>2) + 16*((lane>>3)&1) + 8*(lane&1);
  const short* Vsrc = qkv + (size_t)(b*NS+vk)*3072 + h*64 + 2048 + vd;

  int sw = (q5&7)<<4;
  int baseK = q5*128 + ((hi<<4) ^ (sw&16)) + (sw&96);
  int baseV = hi*512 + lb0*128 + la*8;

  f32x16 cacc0={}, cacc1={};
  float mrow=-1e30f, lrow=0.f;
  const size_t tstep = (size_t)64*3072;

  gload16(Ksrc, Kl + w*1024);
  gload16(Vsrc, Vl + w*1024);
  __syncthreads();
  int cur=0;

  for (int t=0;t<NS/64;t++){
    if (t+1 < NS/64){
      gload16(Ksrc + (size_t)(t+1)*tstep, Kl + (cur^1)*8192 + w*1024);
      gload16(Vsrc + (size_t)(t+1)*tstep, Vl + (cur^1)*8192 + w*1024);
    }
    const char* Kb = Kl + cur*8192;
    f32x16 s0={}, s1={};
    #pragma unroll
    for (int ds=0; ds<4; ds++){
      s16x8 k0 = *(const s16x8*)(Kb + (baseK ^ (ds<<5)));
      s16x8 k1 = *(const s16x8*)(Kb + 4096 + (baseK ^ (ds<<5)));
      s0 = __builtin_amdgcn_mfma_f32_32x32x16_bf16(k0, qf[ds], s0, 0,0,0);
      s1 = __builtin_amdgcn_mfma_f32_32x32x16_bf16(k1, qf[ds], s1, 0,0,0);
    }
    float pmax = s0[0];
    #pragma unroll
    for (int r=1;r<16;r++) pmax = fmaxf(pmax, s0[r]);
    #pragma unroll
    for (int r=0;r<16;r++) pmax = fmaxf(pmax, s1[r]);
    pmax = fmaxf(pmax, __shfl_xor(pmax, 32, 64));
    if (__any(pmax > mrow + 8.f)){
      float mnew = fmaxf(mrow, pmax);
      float corr = __expf(mrow - mnew);
      if (!hi) stats[w*32+q5] = corr;
      LGK;
      lrow *= corr; mrow = mnew;
      #pragma unroll
      for (int r=0;r<16;r++){
        float c = stats[w*32 + ((r&3)+8*(r>>2)+4*hi)];
        cacc0[r]*=c; cacc1[r]*=c;
      }
    }
    float rs = 0.f;
    #pragma unroll
    for (int r=0;r<16;r++){ float p=__expf(s0[r]-mrow); s0[r]=p; rs+=p; }
    #pragma unroll
    for (int r=0;r<16;r++){ float p=__expf(s1[r]-mrow); s1[r]=p; rs+=p; }
    rs += __shfl_xor(rs, 32, 64);
    lrow += rs;
    unsigned int D0[4][2], D1[4][2], R0[4][2], R1[4][2];
    #pragma unroll
    for (int bb=0;bb<4;bb++)
      #pragma unroll
      for (int hh=0;hh<2;hh++){
        D0[bb][hh] = (unsigned int)(unsigned short)f2b(s0[4*bb+2*hh]) |
                     ((unsigned int)(unsigned short)f2b(s0[4*bb+2*hh+1])<<16);
        D1[bb][hh] = (unsigned int)(unsigned short)f2b(s1[4*bb+2*hh]) |
                     ((unsigned int)(unsigned short)f2b(s1[4*bb+2*hh+1])<<16);
      }
    #pragma unroll
    for (int bb=0;bb<4;bb++)
      #pragma unroll
      for (int hh=0;hh<2;hh++){
        R0[bb][hh] = (unsigned int)__shfl_xor((int)D0[bb][hh], 32, 64);
        R1[bb][hh] = (unsigned int)__shfl_xor((int)D1[bb][hh], 32, 64);
      }
    union PA { unsigned int u[4]; s16x8 v; } pa[4];
    #pragma unroll
    for (int e=0;e<2;e++)
      #pragma unroll
      for (int hh=0;hh<2;hh++){
        pa[e].u[hh]     = hi ? R0[2*e+1][hh] : D0[2*e][hh];
        pa[e].u[2+hh]   = hi ? D0[2*e+1][hh] : R0[2*e][hh];
        pa[2+e].u[hh]   = hi ? R1[2*e+1][hh] : D1[2*e][hh];
        pa[2+e].u[2+hh] = hi ? D1[2*e+1][hh] : R1[2*e][hh];
      }
    const char* Vb = Vl + cur*8192;
    #pragma unroll
    for (int ks=0;ks<4;ks++){
      s16x4 t00 = tr16(Vb + ks*1024 +        0 + baseV);
      s16x4 t01 = tr16(Vb + ks*1024 +      256 + baseV);
      s16x4 t10 = tr16(Vb + ks*1024 + 4096     + baseV);
      s16x4 t11 = tr16(Vb + ks*1024 + 4096+256 + baseV);
      LGK;
      union { s16x4 hh[2]; s16x8 v; } u0, u1;
      u0.hh[0]=t00; u0.hh[1]=t01;
      u1.hh[0]=t10; u1.hh[1]=t11;
      cacc0 = __builtin_amdgcn_mfma_f32_32x32x16_bf16(pa[ks].v, u0.v, cacc0, 0,0,0);
      cacc1 = __builtin_amdgcn_mfma_f32_32x32x16_bf16(pa[ks].v, u1.v, cacc1, 0,0,0);
    }
    __syncthreads();
    cur ^= 1;
  }
  if (!hi) stats[w*32+q5] = 1.0f/lrow;
  LGK;
  #pragma unroll
  for (int r=0;r<16;r++){
    int q = (r&3)+8*(r>>2)+4*hi;
    float linv = stats[w*32+q];
    size_t row = (size_t)(b*NS + q0w + q)*DM + h*64;
    ctx[row + q5]      = f2b(cacc0[r]*linv);
    ctx[row + 32 + q5] = f2b(cacc1[r]*linv);
  }
}

// ---------------- LayerNorm kernels ----------------
__device__ __forceinline__ void wred2(float& s, float& ss){
  #pragma unroll
  for (int m=1;m<64;m<<=1){ s += __shfl_xor(s,m,64); ss += __shfl_xor(ss,m,64); }
}

__global__ __launch_bounds__(256) void ln_in(const float* __restrict__ x,
    const float* __restrict__ g, const float* __restrict__ be, short* __restrict__ out)
{
  int row=blockIdx.x, tid=threadIdx.x;
  __shared__ float r1[4], r2[4];
  float4 v = ((const float4*)(x + (size_t)row*DM))[tid];
  float s=v.x+v.y+v.z+v.w, ss=v.x*v.x+v.y*v.y+v.z*v.z+v.w*v.w;
  wred2(s,ss);
  if ((tid&63)==0){ r1[tid>>6]=s; r2[tid>>6]=ss; }
  __syncthreads();
  s=r1[0]+r1[1]+r1[2]+r1[3]; ss=r2[0]+r2[1]+r2[2]+r2[3];
  float mu=s*(1.f/DM);
  float rstd=rsqrtf(ss*(1.f/DM)-mu*mu+1e-5f);
  float4 gv=((const float4*)g)[tid], bv=((const float4*)be)[tid];
  s16x4 o;
  o[0]=f2b((v.x-mu)*rstd*gv.x+bv.x);
  o[1]=f2b((v.y-mu)*rstd*gv.y+bv.y);
  o[2]=f2b((v.z-mu)*rstd*gv.z+bv.z);
  o[3]=f2b((v.w-mu)*rstd*gv.w+bv.w);
  *(s16x4*)(out + (size_t)row*DM + tid*4) = o;
}

// x1 = LN(x + sum(P_i), g1,b1) [f32]; h2 = bf16(LN(x1, g2,b2)); h2 may alias p0 (row-wise RAW safe)
__global__ __launch_bounds__(256) void ln_chain(const float* __restrict__ x,
    const short* __restrict__ p0, const short* __restrict__ p1,
    const short* __restrict__ p2, const short* __restrict__ p3,
    const float* __restrict__ g1, const float* __restrict__ be1,
    const float* __restrict__ g2, const float* __restrict__ be2,
    float* __restrict__ x1, short* __restrict__ h2)
{
  int row=blockIdx.x, tid=threadIdx.x;
  __shared__ float r1[4], r2[4], r3[4], r4[4];
  size_t off = (size_t)row*DM + tid*4;
  float4 xv = ((const float4*)(x + (size_t)row*DM))[tid];
  s16x4 a0=*(const s16x4*)(p0+off), a1=*(const s16x4*)(p1+off);
  s16x4 a2=*(const s16x4*)(p2+off), a3=*(const s16x4*)(p3+off);
  float4 y;
  y.x = xv.x + b2f(a0[0])+b2f(a1[0])+b2f(a2[0])+b2f(a3[0]);
  y.y = xv.y + b2f(a0[1])+b2f(a1[1])+b2f(a2[1])+b2f(a3[1]);
  y.z = xv.z + b2f(a0[2])+b2f(a1[2])+b2f(a2[2])+b2f(a3[2]);
  y.w = xv.w + b2f(a0[3])+b2f(a1[3])+b2f(a2[3])+b2f(a3[3]);
  float s=y.x+y.y+y.z+y.w, ss=y.x*y.x+y.y*y.y+y.z*y.z+y.w*y.w;
  wred2(s,ss);
  if ((tid&63)==0){ r1[tid>>6]=s; r2[tid>>6]=ss; }
  __syncthreads();
  s=r1[0]+r1[1]+r1[2]+r1[3]; ss=r2[0]+r2[1]+r2[2]+r2[3];
  float mu=s*(1.f/DM);
  float rstd=rsqrtf(ss*(1.f/DM)-mu*mu+1e-5f);
  float4 g1v=((const float4*)g1)[tid], b1v=((const float4*)be1)[tid];
  float4 xo;
  xo.x=(y.x-mu)*rstd*g1v.x+b1v.x;
  xo.y=(y.y-mu)*rstd*g1v.y+b1v.y;
  xo.z=(y.z-mu)*rstd*g1v.z+b1v.z;
  xo.w=(y.w-mu)*rstd*g1v.w+b1v.w;
  ((float4*)(x1 + (size_t)row*DM))[tid] = xo;
  float s2=xo.x+xo.y+xo.z+xo.w, ss2=xo.x*xo.x+xo.y*xo.y+xo.z*xo.z+xo.w*xo.w;
  wred2(s2,ss2);
  if ((tid&63)==0){ r3[tid>>6]=s2; r4[tid>>6]=ss2; }
  __syncthreads();
  s2=r3[0]+r3[1]+r3[2]+r3[3]; ss2=r4[0]+r4[1]+r4[2]+r4[3];
  float mu2=s2*(1.f/DM);
  float rstd2=rsqrtf(ss2*(1.f/DM)-mu2*mu2+1e-5f);
  float4 g2v=((const float4*)g2)[tid], b2v=((const float4*)be2)[tid];
  s16x4 o;
  o[0]=f2b((xo.x-mu2)*rstd2*g2v.x+b2v.x);
  o[1]=f2b((xo.y-mu2)*rstd2*g2v.y+b2v.y);
  o[2]=f2b((xo.z-mu2)*rstd2*g2v.z+b2v.z);
  o[3]=f2b((xo.w-mu2)*rstd2*g2v.w+b2v.w);
  *(s16x4*)(h2 + off) = o;
}

// out = LN(x1 + sum(P_i), g, be) [f32]
__global__ __launch_bounds__(256) void ln_out_k(const float* __restrict__ x1,
    const short* __restrict__ p0, const short* __restrict__ p1,
    const short* __restrict__ p2, const short* __restrict__ p3,
    const float* __restrict__ g, const float* __restrict__ be, float* __restrict__ out)
{
  int row=blockIdx.x, tid=threadIdx.x;
  __shared__ float r1[4], r2[4];
  size_t off = (size_t)row*DM + tid*4;
  float4 xv = ((const float4*)(x1 + (size_t)row*DM))[tid];
  s16x4 a0=*(const s16x4*)(p0+off), a1=*(const s16x4*)(p1+off);
  s16x4 a2=*(const s16x4*)(p2+off), a3=*(const s16x4*)(p3+off);
  float4 y;
  y.x = xv.x + b2f(a0[0])+b2f(a1[0])+b2f(a2[0])+b2f(a3[0]);
  y.y = xv.y + b2f(a0[1])+b2f(a1[1])+b2f(a2[1])+b2f(a3[1]);
  y.z = xv.z + b2f(a0[2])+b2f(a1[2])+b2f(a2[2])+b2f(a3[2]);
  y.w = xv.w + b2f(a0[3])+b2f(a1[3])+b2f(a2[3])+b2f(a3[3]);
  float s=y.x+y.y+y.z+y.w, ss=y.x*y.x+y.y*y.y+y.z*y.z+y.w*y.w;
  wred2(s,ss);
  if ((tid&63)==0){ r1[tid>>6]=s; r2[tid>>6]=ss; }
  __syncthreads();
  s=r1[0]+r1[1]+r1[2]+r1[3]; ss=r2[0]+r2[1]+r2[2]+r2[3];
  float mu=s*(1.f/DM);
  float rstd=rsqrtf(ss*(1.f/DM)-mu*mu+1e-5f);
  float4 gv=((const float4*)g)[tid], bv=((const float4*)be)[tid];
  float4 o;
  o.x=(y.x-mu)*rstd*gv.x+bv.x;
  o.y=(y.y-mu)*rstd*gv.y+bv.y;
  o.z=(y.z-mu)*rstd*gv.z+bv.z;
  o.w=(y.w-mu)*rstd*gv.w+bv.w;
  ((float4*)(out + (size_t)row*DM))[tid] = o;
}

// ---------------- cast + transpose: w[R][C] f32 -> wt[C][R] bf16 ----------------
__global__ __launch_bounds__(256) void cast_t(const float* __restrict__ w, short* __restrict__ wt, int R, int C)
{
  __shared__ short t[64][65];
  int nbr = R>>6;
  int br = (int)blockIdx.x % nbr, bc = (int)blockIdx.x / nbr;
  int tid = threadIdx.x;
  #pragma unroll
  for (int i=0;i<4;i++){
    int c = i*256 + tid;
    int r = c>>4, c4 = (c&15)*4;
    float4 v = *(const float4*)(w + (size_t)(br*64 + r)*C + bc*64 + c4);
    t[r][c4+0]=f2b(v.x); t[r][c4+1]=f2b(v.y); t[r][c4+2]=f2b(v.z); t[r][c4+3]=f2b(v.w);
  }
  __syncthreads();
  #pragma unroll
  for (int i=0;i<4;i++){
    int c = i*256 + tid;
    int oc = c>>4, c4 = (c&15)*4;
    s16x4 p;
    p[0]=t[c4+0][oc]; p[1]=t[c4+1][oc]; p[2]=t[c4+2][oc]; p[3]=t[c4+3][oc];
    *(s16x4*)&wt[(size_t)(bc*64 + oc)*R + br*64 + c4] = p;
  }
}

// ---------------- launcher ----------------
// ws layout (bytes; aliveness-checked):
//   w2T    @ 0         (8.39M)   alive: cast..ff2
//   w1T    @ 8388608   (8.39M)   alive: cast..ff1     -> Pff2[0] after
//   woutT  @ 16777216  (2.10M)   alive: cast..outproj -\
//   wqkvT  @ 18874368  (6.29M)   alive: cast..qkvgemm -+-> Pff2[1] @16777216 after
//   h1/h2  @ 25165824  (8.39M)   h1: ln_in..qkv; Pout[0]: outproj..ln_chain; h2: ln_chain..ff1; Pff2[2] after
//   qkv    @ 33554432  (25.17M)  qkv: qkvgemm..attn; Pout[1..3] @33554432+i*8.39M; ff1 @33554432 (33.55M) after
//   ctx    @ 58720256  (8.39M)   attn..outproj (ff1 tail overlaps after)
//   x1     @ 67108864  (16.78M)  f32, ln_chain..ln_out
//   Pff2[3]@ 83886080  (8.39M)
extern "C" void kernel_launch(void* const* d_in, const int* in_sizes, int n_in,
                              void* d_out, int out_size, void* d_ws, size_t ws_size,
                              hipStream_t stream)
{
  const float* x      = (const float*)d_in[0];
  const float* qkv_w  = (const float*)d_in[1];
  const float* qkv_b  = (const float*)d_in[2];
  const float* out_w  = (const float*)d_in[3];
  const float* out_b  = (const float*)d_in[4];
  const float* aln_g  = (const float*)d_in[5];
  const float* aln_b  = (const float*)d_in[6];
  const float* n1_g   = (const float*)d_in[7];
  const float* n1_b   = (const float*)d_in[8];
  const float* fln_g  = (const float*)d_in[9];
  const float* fln_b  = (const float*)d_in[10];
  const float* w1     = (const float*)d_in[11];
  const float* b1     = (const float*)d_in[12];
  const float* w2     = (const float*)d_in[13];
  const float* b2     = (const float*)d_in[14];
  const float* n2_g   = (const float*)d_in[15];
  const float* n2_b   = (const float*)d_in[16];

  char* ws = (char*)d_ws;
  short* w2T   = (short*)(ws + 0);
  short* w1T   = (short*)(ws + 8388608);
  short* woutT = (short*)(ws + 16777216);
  short* wqkvT = (short*)(ws + 18874368);
  short* h1    = (short*)(ws + 25165824);
  short* qkv   = (short*)(ws + 33554432);
  short* ctx   = (short*)(ws + 58720256);
  float* x1    = (float*)(ws + 67108864);
  short* ff1   = (short*)(ws + 33554432);
  short* Po0 = (short*)(ws + 25165824);
  short* Po1 = (short*)(ws + 33554432);
  short* Po2 = (short*)(ws + 41943040);
  short* Po3 = (short*)(ws + 50331648);
  short* Pf0 = (short*)(ws + 8388608);
  short* Pf1 = (short*)(ws + 16777216);
  short* Pf2 = (short*)(ws + 25165824);
  short* Pf3 = (short*)(ws + 83886080);
  float* outp  = (float*)d_out;

  cast_t<<<dim3(16*48),256,0,stream>>>(qkv_w, wqkvT, 1024, 3072);
  cast_t<<<dim3(16*16),256,0,stream>>>(out_w, woutT, 1024, 1024);
  cast_t<<<dim3(16*64),256,0,stream>>>(w1,    w1T,   1024, 4096);
  cast_t<<<dim3(64*16),256,0,stream>>>(w2,    w2T,   4096, 1024);

  ln_in<<<NTOK,256,0,stream>>>(x, aln_g, aln_b, h1);
  gemm8p<0,1><<<dim3(192,1,1),512,0,stream>>>(h1, wqkvT, qkv_b, qkv,qkv,qkv,qkv, 4096,3072,1024);
  attn_fwd<<<dim3(8,32),512,0,stream>>>(qkv, ctx);
  gemm8p<0,4><<<dim3(64,1,4),512,0,stream>>>(ctx, woutT, out_b, Po0,Po1,Po2,Po3, 4096,1024,1024);
  ln_chain<<<NTOK,256,0,stream>>>(x, Po0,Po1,Po2,Po3, n1_g,n1_b, fln_g,fln_b, x1, h1);
  gemm8p<1,1><<<dim3(256,1,1),512,0,stream>>>(h1, w1T, b1, ff1,ff1,ff1,ff1, 4096,4096,1024);
  gemm8p<0,4><<<dim3(64,1,4),512,0,stream>>>(ff1, w2T, b2, Pf0,Pf1,Pf2,Pf3, 4096,1024,4096);
  ln_out_k<<<NTOK,256,0,stream>>>(x1, Pf0,Pf1,Pf2,Pf3, n2_g,n2_b, outp);
}